// Round 7
// baseline (446.982 us; speedup 1.0000x reference)
//
#include <hip/hip_runtime.h>
#include <hip/hip_bf16.h>
#include <cstdint>
#include <cstddef>

// Problem constants (from reference). Inputs/outputs are fp32 (verified round 4).
#define BN_ 2
#define TQ_ 1024
#define TK_ 2048
#define DQ_ 1024
#define DC_ 768
#define NH_ 16
#define DH_ 64
#define TOPK_ 64

typedef unsigned short u16;
typedef __attribute__((ext_vector_type(8))) short short8;   // 8 bf16 MFMA frag
typedef __attribute__((ext_vector_type(8))) u16   ushort8;  // 16B vector load
typedef __attribute__((ext_vector_type(4))) float floatx4;  // MFMA acc / float4

__device__ __forceinline__ float bf2f(u16 u) { return __uint_as_float(((unsigned)u) << 16); }
__device__ __forceinline__ u16 f2bf(float f) {  // round-to-nearest-even (manual)
    unsigned u = __float_as_uint(f);
    u += 0x7FFFu + ((u >> 16) & 1u);
    return (u16)(u >> 16);
}
// HW-converter variant for hot staging loops: compiler emits v_cvt_pk_bf16_f32
// pairs (m240: scalar cast beats hand asm). RNE == RNE -> bit-identical to
// f2bf for all non-NaN inputs (ours are definite).
__device__ __forceinline__ u16 f2bf_cvt(float f) {
    union { __hip_bfloat16 b; u16 u; } cv;
    cv.b = __float2bfloat16(f);
    return cv.u;
}
__device__ __forceinline__ float definite(float v, float repl) {
    return ((__float_as_uint(v) & 0x7F800000u) == 0x7F800000u) ? repl : v;
}
// monotone float<->uint mapping (ascending)
__device__ __forceinline__ unsigned mono(float f) {
    unsigned u = __float_as_uint(f);
    return (u & 0x80000000u) ? ~u : (u | 0x80000000u);
}
__device__ __forceinline__ float invmono(unsigned u) {
    return __uint_as_float((u & 0x80000000u) ? (u & 0x7FFFFFFFu) : ~u);
}
// async global(16B) -> LDS direct copy. LDS dest must be linear in lane
// (base + lane*16); the swizzle lives in the per-lane GLOBAL address
// (m173 pattern: linear LDS dest + pre-swizzled per-lane source).
__device__ __forceinline__ void gld16(const u16* g, u16* l) {
    __builtin_amdgcn_global_load_lds(
        (const __attribute__((address_space(1))) unsigned*)g,
        (__attribute__((address_space(3))) unsigned*)l, 16, 0, 0);
}
// 16-lane-group reductions (xor offsets 1,2,4,8 stay inside row-of-16 -> DPP)
__device__ __forceinline__ int gsum16(int x) {
#pragma unroll
    for (int o = 1; o < 16; o <<= 1) x += __shfl_xor(x, o);
    return x;
}
__device__ __forceinline__ int gmin16(int x) {
#pragma unroll
    for (int o = 1; o < 16; o <<= 1) { int y = __shfl_xor(x, o); x = (y < x) ? y : x; }
    return x;
}
__device__ __forceinline__ unsigned gmin16u(unsigned x) {
#pragma unroll
    for (int o = 1; o < 16; o <<= 1) { unsigned y = __shfl_xor((int)x, o); x = (y < x) ? y : x; }
    return x;
}
__device__ __forceinline__ unsigned gmax16u(unsigned x) {
#pragma unroll
    for (int o = 1; o < 16; o <<= 1) { unsigned y = __shfl_xor((int)x, o); x = (y > x) ? y : x; }
    return x;
}
__device__ __forceinline__ float gmax16f(float x) {
#pragma unroll
    for (int o = 1; o < 16; o <<= 1) x = fmaxf(x, __shfl_xor(x, o));
    return x;
}
__device__ __forceinline__ float gsum16f(float x) {
#pragma unroll
    for (int o = 1; o < 16; o <<= 1) x += __shfl_xor(x, o);
    return x;
}
// LDS bank-conflict swizzle for the qtr0 logit region (round-21).
// Hot patterns: logit STORES hit rows quad*4+r (quads 4 rows apart); um LOADS
// hit rows wave*4+quad (quads 1 row apart). Row stride 512 dwords is
// bank-invariant -> both were 4-way conflicts (6.6M conflict cycles, ~5%).
// swz places (row&1)^((row>>2)&1) into bank bit4 and (row>>1)&1 into bit2:
// hand-checked, both patterns become 2-way (= free, m136). XOR is a
// bijection; um[j] still holds key (l16+16j)'s logit -> select bit-identical.
__device__ __forceinline__ int lgswz(int row) {
    return ((((row >> 2) ^ row) & 1) << 4) | (((row >> 1) & 1) << 2);
}

// diagnostic: fill output with a recognizable constant (fp32 out)
__global__ void marker_kernel(float* __restrict__ out, int n, float val) {
    const int i = blockIdx.x * 256 + threadIdx.x;
    if (i < n) out[i] = val;
}

// ---------------------------------------------------------------------------
// Exact top-64 selection, qtr0 variant: 32 values/lane with IMPLICIT keys
// key(j) = (l16 + 16*j) << 11 (pre-scaled V byte offset, affine in register
// index j — no kk[32] array, which was the residual spill source at 64 VGPR).
// Early-exit when count==64 ({u >= X} exactly 64). Compact >X then tie-fill
// ==X ascending-key. Returns xval = invmono(X) (lower bound on kept min).
__device__ __forceinline__ float select_topk32_ik(const unsigned (&um)[32], int l16,
                                                  float* cvrow, int* ckrow) {
    unsigned X = 0u;
    bool done = false;
    for (int bit = 31; bit >= 0; --bit) {
        const unsigned C = X | (1u << bit);
        int c = 0;
#pragma unroll
        for (int j = 0; j < 32; ++j) c += (um[j] >= C) ? 1 : 0;
        c = gsum16(c);
        if (!done && c >= 64) X = C;
        if (c == 64) done = true;
        if (__all(done)) break;
    }
    // compact strictly-greater
    int myGt = 0;
#pragma unroll
    for (int j = 0; j < 32; ++j) myGt += (um[j] > X) ? 1 : 0;
    const int totalGt = gsum16(myGt);
    int pre = myGt;
#pragma unroll
    for (int off = 1; off < 16; off <<= 1) {
        const int tv = __shfl_up(pre, off);
        if (l16 >= off) pre += tv;
    }
    int wpos = pre - myGt;
#pragma unroll
    for (int j = 0; j < 32; ++j) {
        if (um[j] > X) {
            cvrow[wpos] = invmono(um[j]);
            ckrow[wpos] = (l16 + 16 * j) << 11;
            ++wpos;
        }
    }
    // tie-fill remaining slots with ==X entries, ascending key
    const float xval = invmono(X);
    int remaining = 64 - totalGt;
    int pos = totalGt;
    int lastkey = -1;
    while (remaining > 0) {
        int mykey = 0x7FFFFFFF;
#pragma unroll
        for (int j = 0; j < 32; ++j) {
            const int kj = (l16 + 16 * j) << 11;
            if (um[j] == X && kj > lastkey && kj < mykey) mykey = kj;
        }
        const int mn = gmin16(mykey);
        if (mn == 0x7FFFFFFF) break;
        if (mykey == mn) { cvrow[pos] = xval; ckrow[pos] = mn; }
        lastkey = mn;
        ++pos; --remaining;
    }
    return xval;
}

// ---------------------------------------------------------------------------
// Compact-phase select: NV values/lane (explicit scaled keys), z-space vs
// base. Same algorithm; writes separate value/key arrays.
template <int NV>
__device__ __forceinline__ float select_topk(const unsigned (&um)[NV], const int (&kk)[NV],
                                             unsigned base, int hb, int l16,
                                             float* cvrow, int* ckrow) {
    unsigned X = 0u;
    bool done = false;
    for (int bit = hb; bit >= 0; --bit) {
        const unsigned C = X | (1u << bit);
        int c = 0;
#pragma unroll
        for (int j = 0; j < NV; ++j) c += (um[j] >= C) ? 1 : 0;
        c = gsum16(c);
        if (!done && c >= 64) X = C;
        if (c == 64) done = true;
        if (__all(done)) break;
    }
    int myGt = 0;
#pragma unroll
    for (int j = 0; j < NV; ++j) myGt += (um[j] > X) ? 1 : 0;
    const int totalGt = gsum16(myGt);
    int pre = myGt;
#pragma unroll
    for (int off = 1; off < 16; off <<= 1) {
        const int tv = __shfl_up(pre, off);
        if (l16 >= off) pre += tv;
    }
    int wpos = pre - myGt;
#pragma unroll
    for (int j = 0; j < NV; ++j) {
        if (um[j] > X) {
            cvrow[wpos] = invmono(base + um[j]);
            ckrow[wpos] = kk[j];
            ++wpos;
        }
    }
    const float xval = invmono(base + X);
    int remaining = 64 - totalGt;
    int pos = totalGt;
    int lastkey = -1;
    while (remaining > 0) {
        int mykey = 0x7FFFFFFF;
#pragma unroll
        for (int j = 0; j < NV; ++j)
            if (um[j] == X && kk[j] > lastkey && kk[j] < mykey) mykey = kk[j];
        const int mn = gmin16(mykey);
        if (mn == 0x7FFFFFFF) break;
        if (mykey == mn) { cvrow[pos] = xval; ckrow[pos] = mn; }
        lastkey = mn;
        ++pos; --remaining;
    }
    return xval;
}

// ---------------------------------------------------------------------------
// Transpose + hi/lo-split: W fp32 [K][N] -> Wh,Wl bf16 [N][K]
// Batched variant: blockIdx.z selects among up to 3 independent weights
// (saves 2 kernel launches + stream bubbles vs separate dispatches).
struct TsplitJob { const float* W; u16* Wh; u16* Wl; int K; int N; };

__global__ void __launch_bounds__(256) tsplit3(TsplitJob j0, TsplitJob j1, TsplitJob j2) {
    const TsplitJob j = (blockIdx.z == 0) ? j0 : (blockIdx.z == 1) ? j1 : j2;
    const int bk = blockIdx.y * 32;
    if (bk >= j.K) return;                      // grids padded to max K/32
    __shared__ float t[32][33];
    const int x = threadIdx.x & 31, y = threadIdx.x >> 5;   // y in 0..7
    const int bn = blockIdx.x * 32;
#pragma unroll
    for (int i = 0; i < 32; i += 8) t[y + i][x] = j.W[(size_t)(bk + y + i) * j.N + bn + x];
    __syncthreads();
#pragma unroll
    for (int i = 0; i < 32; i += 8) {
        const float f = t[x][y + i];            // = W[bk+x][bn+y+i]
        const u16 hi = f2bf(f);
        const size_t o = (size_t)(bn + y + i) * j.K + bk + x;
        j.Wh[o] = hi;
        j.Wl[o] = f2bf(f - bf2f(hi));
    }
}

__global__ void __launch_bounds__(256) tsplit(const float* __restrict__ W,
                                              u16* __restrict__ Wh, u16* __restrict__ Wl,
                                              int K, int N) {
    __shared__ float t[32][33];
    const int x = threadIdx.x & 31, y = threadIdx.x >> 5;
    const int bn = blockIdx.x * 32, bk = blockIdx.y * 32;
#pragma unroll
    for (int i = 0; i < 32; i += 8) t[y + i][x] = W[(size_t)(bk + y + i) * N + bn + x];
    __syncthreads();
#pragma unroll
    for (int i = 0; i < 32; i += 8) {
        const float f = t[x][y + i];
        const u16 hi = f2bf(f);
        const size_t o = (size_t)(bn + y + i) * K + bk + x;
        Wh[o] = hi;
        Wl[o] = f2bf(f - bf2f(hi));
    }
}

// ---------------------------------------------------------------------------
// GEMM (round-11 proven structure; r19: global_load_lds staging for pre-split
// operands; r21: A-split conversion via HW cvt (v_cvt_pk_bf16_f32) — RNE
// bit-identical to manual f2bf, fewer VALU ops in the hot staging loop).
// C[M][N] = A[M][K] * W[K][N] + bias, * scale.
// B pre-transposed & split: Bh/Bl bf16 [N][K]. Tile 64(M) x 128(N), BK=64.
// XOR-swizzled UNPADDED LDS: row m chunk c stored at slot m*8 + (c ^ (m&7)).
// 4 waves 2x2: wave tile 32(m) x 64(n) = 2x4 mfma_16x16x32, 3-term split
// (ah*bh + al*bh + ah*bl). LDS 48KB -> 3 WG/CU.
// ASPLIT 0: A fp32 (split at stage). ASPLIT 1: A bf16 hi/lo (global_load_lds).
// OMODE 0: fp32 out. 1: bf16 out. 2: hi/lo pair out.
template <int ASPLIT, int OMODE>
__global__ void __launch_bounds__(256) gemm3(
    const void* __restrict__ Ap, const void* __restrict__ Alp,
    const u16* __restrict__ Bh, const u16* __restrict__ Bl,
    const float* __restrict__ bias, float scale,
    void* __restrict__ out0, void* __restrict__ out1,
    int M, int N, int K) {
    __shared__ u16 Ahs[64 * 64];    // 8 KB   [m][k] hi, swizzled
    __shared__ u16 Als[64 * 64];    // 8 KB   lo
    __shared__ u16 Bhs[128 * 64];   // 16 KB  [n][k] hi, swizzled
    __shared__ u16 Bls[128 * 64];   // 16 KB  lo

    const int tid = threadIdx.x;
    const int lane = tid & 63, wave = tid >> 6;
    const int wm = wave >> 1, wn = wave & 1;
    const int quad = lane >> 4, l16 = lane & 15;
    const int bm = blockIdx.y * 64, bn = blockIdx.x * 128;

    floatx4 acc[2][4] = {};

    for (int k0 = 0; k0 < K; k0 += 64) {
        __syncthreads();
        // ---- stage A: 64 rows x 64 cols = 512 slots of 8 elems, 2 per thread
#pragma unroll
        for (int s2 = 0; s2 < 2; ++s2) {
            const int slot = tid + s2 * 256;
            const int m = slot >> 3, cpos = slot & 7;
            const int c = cpos ^ (m & 7);
            const size_t aoff = (size_t)(bm + m) * K + k0 + c * 8;
            if constexpr (ASPLIT == 0) {
                const float* f = (const float*)Ap + aoff;
                const floatx4 a = *(const floatx4*)f;
                const floatx4 b = *(const floatx4*)(f + 4);
                ushort8 hi, lo;
#pragma unroll
                for (int j = 0; j < 4; ++j) {
                    const u16 t = f2bf_cvt(a[j]);
                    hi[j] = t; lo[j] = f2bf_cvt(a[j] - bf2f(t));
                    const u16 t2 = f2bf_cvt(b[j]);
                    hi[4 + j] = t2; lo[4 + j] = f2bf_cvt(b[j] - bf2f(t2));
                }
                *(ushort8*)&Ahs[slot * 8] = hi;
                *(ushort8*)&Als[slot * 8] = lo;
            } else {
                gld16((const u16*)Ap  + aoff, &Ahs[slot * 8]);
                gld16((const u16*)Alp + aoff, &Als[slot * 8]);
            }
        }
        // ---- stage B: 128 rows x 64 cols = 1024 slots, 4 per thread,
        //      async direct-to-LDS (dest linear in lane; swizzle in gaddr)
#pragma unroll
        for (int s4 = 0; s4 < 4; ++s4) {
            const int slot = tid + s4 * 256;
            const int n = slot >> 3, cpos = slot & 7;
            const int c = cpos ^ (n & 7);
            const size_t boff = (size_t)(bn + n) * K + k0 + c * 8;
            gld16(Bh + boff, &Bhs[slot * 8]);
            gld16(Bl + boff, &Bls[slot * 8]);
        }
        __syncthreads();
#pragma unroll
        for (int s = 0; s < 2; ++s) {
            short8 ah[2], al[2], bh[4], bl[4];
#pragma unroll
            for (int mt = 0; mt < 2; ++mt) {
                const int m = wm * 32 + mt * 16 + l16;
                const int cs = s * 4 + quad;
                const int slot = m * 8 + (cs ^ (m & 7));
                ah[mt] = *(const short8*)&Ahs[slot * 8];
                al[mt] = *(const short8*)&Als[slot * 8];
            }
#pragma unroll
            for (int nt = 0; nt < 4; ++nt) {
                const int n = wn * 64 + nt * 16 + l16;
                const int cs = s * 4 + quad;
                const int slot = n * 8 + (cs ^ (n & 7));
                bh[nt] = *(const short8*)&Bhs[slot * 8];
                bl[nt] = *(const short8*)&Bls[slot * 8];
            }
#pragma unroll
            for (int mt = 0; mt < 2; ++mt)
#pragma unroll
                for (int nt = 0; nt < 4; ++nt) {
                    acc[mt][nt] = __builtin_amdgcn_mfma_f32_16x16x32_bf16(ah[mt], bh[nt], acc[mt][nt], 0, 0, 0);
                    acc[mt][nt] = __builtin_amdgcn_mfma_f32_16x16x32_bf16(al[mt], bh[nt], acc[mt][nt], 0, 0, 0);
                    acc[mt][nt] = __builtin_amdgcn_mfma_f32_16x16x32_bf16(ah[mt], bl[nt], acc[mt][nt], 0, 0, 0);
                }
        }
    }

#pragma unroll
    for (int mt = 0; mt < 2; ++mt) {
#pragma unroll
        for (int nt = 0; nt < 4; ++nt) {
            const int col = bn + wn * 64 + nt * 16 + l16;
            const float bcol = bias[col];
#pragma unroll
            for (int r = 0; r < 4; ++r) {
                const int row = bm + wm * 32 + mt * 16 + quad * 4 + r;
                const float val = definite((acc[mt][nt][r] + bcol) * scale, 0.0f);
                const size_t idx = (size_t)row * N + col;
                if constexpr (OMODE == 0) {
                    ((float*)out0)[idx] = val;
                } else if constexpr (OMODE == 1) {
                    ((u16*)out0)[idx] = f2bf(val);
                } else {
                    const u16 hi = f2bf(val);
                    ((u16*)out0)[idx] = hi;
                    ((u16*)out1)[idx] = f2bf(val - bf2f(hi));
                }
            }
        }
    }
}

// ---------------------------------------------------------------------------
// Batched K+V projection: one launch, blockIdx.z selects the job. Both jobs
// share A = ctx (fp32, split at stage with HW cvt), M, N, K; differ in
// B/bias/out/omode. NOTE: WkT/WvT live in d_out (dead until final GEMM).
struct GemmKVJob { const u16* Bh; const u16* Bl; const float* bias;
                   void* out0; void* out1; int omode; };

__global__ void __launch_bounds__(256) gemm_kv(
    const float* __restrict__ Ap, GemmKVJob j0, GemmKVJob j1,
    int M, int N, int K) {
    const GemmKVJob j = (blockIdx.z == 0) ? j0 : j1;
    __shared__ u16 Ahs[64 * 64];
    __shared__ u16 Als[64 * 64];
    __shared__ u16 Bhs[128 * 64];
    __shared__ u16 Bls[128 * 64];

    const int tid = threadIdx.x;
    const int lane = tid & 63, wave = tid >> 6;
    const int wm = wave >> 1, wn = wave & 1;
    const int quad = lane >> 4, l16 = lane & 15;
    const int bm = blockIdx.y * 64, bn = blockIdx.x * 128;

    floatx4 acc[2][4] = {};

    for (int k0 = 0; k0 < K; k0 += 64) {
        __syncthreads();
#pragma unroll
        for (int s2 = 0; s2 < 2; ++s2) {
            const int slot = tid + s2 * 256;
            const int m = slot >> 3, cpos = slot & 7;
            const int c = cpos ^ (m & 7);
            const size_t aoff = (size_t)(bm + m) * K + k0 + c * 8;
            const float* f = Ap + aoff;
            const floatx4 a = *(const floatx4*)f;
            const floatx4 b = *(const floatx4*)(f + 4);
            ushort8 hi, lo;
#pragma unroll
            for (int jj = 0; jj < 4; ++jj) {
                const u16 t = f2bf_cvt(a[jj]);
                hi[jj] = t; lo[jj] = f2bf_cvt(a[jj] - bf2f(t));
                const u16 t2 = f2bf_cvt(b[jj]);
                hi[4 + jj] = t2; lo[4 + jj] = f2bf_cvt(b[jj] - bf2f(t2));
            }
            *(ushort8*)&Ahs[slot * 8] = hi;
            *(ushort8*)&Als[slot * 8] = lo;
        }
#pragma unroll
        for (int s4 = 0; s4 < 4; ++s4) {
            const int slot = tid + s4 * 256;
            const int n = slot >> 3, cpos = slot & 7;
            const int c = cpos ^ (n & 7);
            const size_t boff = (size_t)(bn + n) * K + k0 + c * 8;
            gld16(j.Bh + boff, &Bhs[slot * 8]);
            gld16(j.Bl + boff, &Bls[slot * 8]);
        }
        __syncthreads();
#pragma unroll
        for (int s = 0; s < 2; ++s) {
            short8 ah[2], al[2], bh[4], bl[4];
#pragma unroll
            for (int mt = 0; mt < 2; ++mt) {
                const int m = wm * 32 + mt * 16 + l16;
                const int cs = s * 4 + quad;
                const int slot = m * 8 + (cs ^ (m & 7));
                ah[mt] = *(const short8*)&Ahs[slot * 8];
                al[mt] = *(const short8*)&Als[slot * 8];
            }
#pragma unroll
            for (int nt = 0; nt < 4; ++nt) {
                const int n = wn * 64 + nt * 16 + l16;
                const int cs = s * 4 + quad;
                const int slot = n * 8 + (cs ^ (n & 7));
                bh[nt] = *(const short8*)&Bhs[slot * 8];
                bl[nt] = *(const short8*)&Bls[slot * 8];
            }
#pragma unroll
            for (int mt = 0; mt < 2; ++mt)
#pragma unroll
                for (int nt = 0; nt < 4; ++nt) {
                    acc[mt][nt] = __builtin_amdgcn_mfma_f32_16x16x32_bf16(ah[mt], bh[nt], acc[mt][nt], 0, 0, 0);
                    acc[mt][nt] = __builtin_amdgcn_mfma_f32_16x16x32_bf16(al[mt], bh[nt], acc[mt][nt], 0, 0, 0);
                    acc[mt][nt] = __builtin_amdgcn_mfma_f32_16x16x32_bf16(ah[mt], bl[nt], acc[mt][nt], 0, 0, 0);
                }
        }
    }

#pragma unroll
    for (int mt = 0; mt < 2; ++mt) {
#pragma unroll
        for (int nt = 0; nt < 4; ++nt) {
            const int col = bn + wn * 64 + nt * 16 + l16;
            const float bcol = j.bias[col];
#pragma unroll
            for (int r = 0; r < 4; ++r) {
                const int row = bm + wm * 32 + mt * 16 + quad * 4 + r;
                const float val = definite(acc[mt][nt][r] + bcol, 0.0f);
                const size_t idx = (size_t)row * N + col;
                if (j.omode == 1) {
                    ((u16*)j.out0)[idx] = f2bf(val);
                } else {
                    const u16 hi = f2bf(val);
                    ((u16*)j.out0)[idx] = hi;
                    ((u16*)j.out1)[idx] = f2bf(val - bf2f(hi));
                }
            }
        }
    }
}

// ---------------------------------------------------------------------------
// Fused attention (round-21: LDS-conflict swizzle + XCD-aware block swizzle).
// Cross-round ledger (attn us / occ% / WRITE MB):
//   r14 40960 LDS:            237 / 44 / 31
//   r17 no bounds:            315 / 23 / 8    (occ halved — occupancy matters)
//   r18 safe cuts:            218 / 43 / 16
//   r20 32768 LDS, zero spill:215.6/ 43 / 8   <- 5th WG did NOT appear at
//     32768B + VGPR 64 + zero spill => 4 WG/CU is the hw ceiling. CLOSED.
// Stall budget: issue ~17us vs measured ~107us/round => latency/structure
// bound. This round attacks the two counter-visible residuals:
//   * SQ_LDS_BANK_CONFLICT 6.6M (~5%): qtr0 logit stores + um loads were
//     4-way conflicts (row stride 512 dwords is bank-invariant). Fixed via
//     lgswz() col-XOR on exactly those two patterns — selection bit-identical
//     (XOR bijection; um[j] still holds key l16+16j's logit).
//   * FETCH 100MB vs ~33MB inputs (3x refetch): grid round-robined q-tiles
//     of the same (h,b) across all 8 XCDs. XCD-aware bijective remap
//     (2048%8==0) clusters each XCD onto 4 (h,b) pairs -> K/V 3MB < 4MB L2.
// Everything else frozen at r20.
__global__ void __launch_bounds__(256, 4) attn_topk(
    const u16* Qhi, const u16* Qlo,     // aliased with outputs - no __restrict__
    const u16* __restrict__ Khi, const u16* __restrict__ Klo,
    const u16* __restrict__ Vb16, const void* __restrict__ maskp,
    u16* attnH, u16* attnL) {
    __shared__ float lg[16][512];     // 32768 B total (carry aliased inside)

#define CV_(row) (&lg[row][256])
#define CK_(row) (((int*)&lg[row][0]) + 320)

    const int tid = threadIdx.x;
    const int lane = tid & 63, wave = tid >> 6;
    const int quad = lane >> 4, l16 = lane & 15;
    const int rowg = wave * 4 + quad;              // this lane's selection row
    // XCD-aware bijective block remap: flat%8 = XCD (round-robin dispatch);
    // each XCD gets a contiguous swz-range = 4 (h,b) pairs of K/V.
    const int flat = blockIdx.x + 64 * (blockIdx.y + 16 * blockIdx.z);
    const int swzb = (flat & 7) * 256 + (flat >> 3);
    const int b = swzb >> 10, h = (swzb >> 6) & 15, q0 = (swzb & 63) * 16;
    const int sRow = lgswz(rowg);                  // this lane's um-load swizzle

    // ---- mask dtype probe: per-wave, barrier-free (first 1024 u16 = 2 KB)
    int mmode;
    {
        bool cbyte = false, cbf = false, cf32 = false;
#pragma unroll
        for (int j = 0; j < 16; ++j) {
            const int i = lane + 64 * j;
            const unsigned v = ((const u16*)maskp)[i];
            cbyte |= (v == 0x0100u || v == 0x0101u) || ((i & 1) && v == 0x0001u);
            cbf   |= (!(i & 1)) && v == 0x3F80u;
            cf32  |= (i & 1) && v == 0x3F80u;
        }
        const bool abf = __any(cbf), af32 = __any(cf32), abyte = __any(cbyte);
        mmode = abf ? 2 : (af32 ? 3 : (abyte ? 1 : 0));
    }

    // ---- Q fragments (A-operand: m=lane&15, k=quad*8+j), two k-steps of 32
    short8 qh[2], ql[2];
    {
        const size_t base = (size_t)(b * TQ_ + q0 + l16) * DQ_ + h * DH_ + quad * 8;
        qh[0] = *(const short8*)(Qhi + base);
        qh[1] = *(const short8*)(Qhi + base + 32);
        ql[0] = *(const short8*)(Qlo + base);
        ql[1] = *(const short8*)(Qlo + base + 32);
    }

    for (int qtr = 0; qtr < 4; ++qtr) {
        if (qtr == 0) {
            // ---- full logit phase: write all 512 per row (bank-swizzled)
#pragma unroll 2
            for (int t = 0; t < 8; ++t) {
                const int key = wave * 128 + t * 16 + l16;
                const size_t kb = (size_t)(b * TK_ + key) * DQ_ + h * DH_ + quad * 8;
                const short8 kh0 = *(const short8*)(Khi + kb);
                const short8 kh1 = *(const short8*)(Khi + kb + 32);
                const short8 kl0 = *(const short8*)(Klo + kb);
                const short8 kl1 = *(const short8*)(Klo + kb + 32);
                floatx4 acc = {};
                acc = __builtin_amdgcn_mfma_f32_16x16x32_bf16(qh[0], kh0, acc, 0, 0, 0);
                acc = __builtin_amdgcn_mfma_f32_16x16x32_bf16(ql[0], kh0, acc, 0, 0, 0);
                acc = __builtin_amdgcn_mfma_f32_16x16x32_bf16(qh[0], kl0, acc, 0, 0, 0);
                acc = __builtin_amdgcn_mfma_f32_16x16x32_bf16(qh[1], kh1, acc, 0, 0, 0);
                acc = __builtin_amdgcn_mfma_f32_16x16x32_bf16(ql[1], kh1, acc, 0, 0, 0);
                acc = __builtin_amdgcn_mfma_f32_16x16x32_bf16(qh[1], kl1, acc, 0, 0, 0);
                const int midx = b * TK_ + key;
                bool masked;
                if (mmode == 2)      masked = ((const u16*)maskp)[midx] != 0;
                else if (mmode == 3) masked = ((const float*)maskp)[midx] != 0.0f;
                else if (mmode == 1) masked = ((const unsigned char*)maskp)[midx] != 0;
                else                 masked = ((const int*)maskp)[midx] != 0;
#pragma unroll
                for (int r = 0; r < 4; ++r) {
                    const int row = quad * 4 + r;
                    lg[row][key ^ lgswz(row)] = masked ? -3.0e38f : acc[r];
                }
            }
            __syncthreads();

            // ---- full select over 32 new values, implicit keys (carry is
            // -inf in qtr0 and provably never selected: every logit >= -3e38)
            unsigned um[32];
#pragma unroll
            for (int j = 0; j < 32; ++j)
                um[j] = mono(lg[rowg][(l16 + 16 * j) ^ sRow]);
            const float th = select_topk32_ik(um, l16, CV_(rowg), CK_(rowg));
            if (l16 == 0) {
                lg[rowg][255] = th;                 // filter threshold for next qtr
                ((int*)&lg[rowg][0])[511] = 0;      // reset candidate counter
            }
        } else {
            // ---- filtered logit phase: push only survivors (> th) compactly
            float cmrow[4];
#pragma unroll
            for (int r = 0; r < 4; ++r) cmrow[r] = lg[quad * 4 + r][255];
#pragma unroll 2
            for (int t = 0; t < 8; ++t) {
                const int key = qtr * 512 + wave * 128 + t * 16 + l16;
                const size_t kb = (size_t)(b * TK_ + key) * DQ_ + h * DH_ + quad * 8;
                const short8 kh0 = *(const short8*)(Khi + kb);
                const short8 kh1 = *(const short8*)(Khi + kb + 32);
                const short8 kl0 = *(const short8*)(Klo + kb);
                const short8 kl1 = *(const short8*)(Klo + kb + 32);
                floatx4 acc = {};
                acc = __builtin_amdgcn_mfma_f32_16x16x32_bf16(qh[0], kh0, acc, 0, 0, 0);
                acc = __builtin_amdgcn_mfma_f32_16x16x32_bf16(ql[0], kh0, acc, 0, 0, 0);
                acc = __builtin_amdgcn_mfma_f32_16x16x32_bf16(qh[0], kl0, acc, 0, 0, 0);
                acc = __builtin_amdgcn_mfma_f32_16x16x32_bf16(qh[1], kh1, acc, 0, 0, 0);
                acc = __builtin_amdgcn_mfma_f32_16x16x32_bf16(ql[1], kh1, acc, 0, 0, 0);
                acc = __builtin_amdgcn_mfma_f32_16x16x32_bf16(qh[1], kl1, acc, 0, 0, 0);
                const int midx = b * TK_ + key;
                bool masked;
                if (mmode == 2)      masked = ((const u16*)maskp)[midx] != 0;
                else if (mmode == 3) masked = ((const float*)maskp)[midx] != 0.0f;
                else if (mmode == 1) masked = ((const unsigned char*)maskp)[midx] != 0;
                else                 masked = ((const int*)maskp)[midx] != 0;
#pragma unroll
                for (int r = 0; r < 4; ++r) {
                    const float val = masked ? -3.0e38f : acc[r];
                    if (val > cmrow[r]) {
                        const int row = quad * 4 + r;
                        const int pos = atomicAdd((int*)&lg[row][511], 1);
                        if (pos < 127) {
                            lg[row][pos] = val;
                            ((int*)&lg[row][0])[128 + pos] = key << 11;
                        }
                    }
                }
            }
            __syncthreads();

            // ---- compact select: 8 candidates + 4 carry per lane, z-space
            unsigned uc[4]; int ck4[4];
#pragma unroll
            for (int t = 0; t < 4; ++t) {
                uc[t] = mono(CV_(rowg)[l16 + 16 * t]);
                ck4[t] = CK_(rowg)[l16 + 16 * t];
            }
            unsigned cm = uc[0];
            cm = (uc[1] < cm) ? uc[1] : cm;
            cm = (uc[2] < cm) ? uc[2] : cm;
            cm = (uc[3] < cm) ? uc[3] : cm;
            cm = gmin16u(cm);
            int cnt = ((int*)&lg[rowg][0])[511];
            if (cnt > 127) cnt = 127;

            unsigned zm[12]; int kk[12];
            unsigned zmx = 0;
#pragma unroll
            for (int i = 0; i < 8; ++i) {
                const int idx = l16 + 16 * i;          // 0..127
                const bool valid = idx < cnt;
                const float v = lg[rowg][idx];
                const int k = ((int*)&lg[rowg][0])[128 + idx];
                const unsigned mv = mono(v);
                // CLAMP: th (early-exit X) can sit below the true carry-min cm;
                // mv <= cm candidates can never be in the exact top-64 -> pads.
                const bool live = valid && (mv > cm);
                zm[i] = live ? (mv - cm) : 0u;
                kk[i] = live ? k : 0x7FFFFFFF;
                zmx = (zm[i] > zmx) ? zm[i] : zmx;
            }
#pragma unroll
            for (int t = 0; t < 4; ++t) {
                zm[8 + t] = uc[t] - cm;
                kk[8 + t] = ck4[t];
                zmx = (zm[8 + t] > zmx) ? zm[8 + t] : zmx;
            }
            zmx = gmax16u(zmx);
            const int hb = 31 - __clz(zmx | 1u);
            const float th = select_topk<12>(zm, kk, cm, hb, l16, CV_(rowg), CK_(rowg));
            if (l16 == 0) {
                lg[rowg][255] = th;
                ((int*)&lg[rowg][0])[511] = 0;
            }
        }
        if (qtr < 3) __syncthreads();   // th/counter + lg reuse next quarter
    }

    // ---- softmax over 64 kept entries (group-parallel; same-wave LDS ordering)
    {
        float v4[4];
#pragma unroll
        for (int t = 0; t < 4; ++t) v4[t] = CV_(rowg)[l16 + 16 * t];
        float m = fmaxf(fmaxf(v4[0], v4[1]), fmaxf(v4[2], v4[3]));
        m = gmax16f(m);
        float p4[4], S = 0.f;
#pragma unroll
        for (int t = 0; t < 4; ++t) { p4[t] = __expf(v4[t] - m); S += p4[t]; }
        S = gsum16f(S);
        const float inv = 1.0f / S;
#pragma unroll
        for (int t = 0; t < 4; ++t) CV_(rowg)[l16 + 16 * t] = p4[t] * inv;
    }

    // ---- weighted bf16-V gather: row-pairs, dword loads (2 dims/lane).
    // Carry keys are pre-scaled V byte offsets -> no per-entry 64-bit
    // multiply; bf16 unpack is 1 shl + 1 and.
    const int half = lane >> 5, l32 = lane & 31;
    const char* Vrow = (const char*)(Vb16 + (size_t)b * TK_ * DQ_ + h * DH_ + l32 * 2);
#pragma unroll
    for (int rp = 0; rp < 2; ++rp) {
        const int row = wave * 4 + rp * 2 + half;
        float a0 = 0.f, a1 = 0.f;
#pragma unroll 4
        for (int e = 0; e < 64; ++e) {
            const float w = CV_(row)[e];
            const int koff = CK_(row)[e];
            const unsigned v2 = *(const unsigned*)(Vrow + koff);
            a0 = fmaf(w, __uint_as_float(v2 << 16), a0);
            a1 = fmaf(w, __uint_as_float(v2 & 0xFFFF0000u), a1);
        }
        a0 = definite(a0, 0.0f);
        a1 = definite(a1, 0.0f);
        const size_t o = (size_t)(b * TQ_ + q0 + row) * DQ_ + h * DH_ + l32 * 2;
        const u16 h0 = f2bf(a0), h1 = f2bf(a1);
        const u16 l0 = f2bf(a0 - bf2f(h0)), l1 = f2bf(a1 - bf2f(h1));
        *(unsigned*)(attnH + o) = (unsigned)h0 | ((unsigned)h1 << 16);
        *(unsigned*)(attnL + o) = (unsigned)l0 | ((unsigned)l1 << 16);
    }
#undef CV_
#undef CK_
}

// ---------------------------------------------------------------------------
extern "C" void kernel_launch(void* const* d_in, const int* in_sizes, int n_in,
                              void* d_out, int out_size, void* d_ws, size_t ws_size,
                              hipStream_t stream) {
    static const int exp_sizes[11] = {2097152, 3145728, 4096, 1048576, 1024,
                                      786432, 1024, 786432, 1024, 1048576, 1024};
    if (n_in != 11) {
        marker_kernel<<<(out_size + 255) / 256, 256, 0, stream>>>((float*)d_out, out_size,
                                                                  (float)(150 + n_in));
        return;
    }
    for (int i = 0; i < 11; ++i)
        if (in_sizes[i] != exp_sizes[i]) {
            marker_kernel<<<(out_size + 255) / 256, 256, 0, stream>>>((float*)d_out, out_size,
                                                                      (float)(200 + i));
            return;
        }

    const float* x   = (const float*)d_in[0];
    const float* ctx = (const float*)d_in[1];
    const void*  msk = d_in[2];
    const float* Wq = (const float*)d_in[3];
    const float* bq = (const float*)d_in[4];
    const float* Wk = (const float*)d_in[5];
    const float* bk = (const float*)d_in[6];
    const float* Wv = (const float*)d_in[7];
    const float* bv = (const float*)d_in[8];
    const float* Wo = (const float*)d_in[9];
    const float* bo = (const float*)d_in[10];

    // ---- workspace: exactly 32 MB (verified sufficient)
    const size_t SZ_Q = (size_t)BN_ * TQ_ * DQ_ * 2;   // 4 MB
    const size_t SZ_K = (size_t)BN_ * TK_ * DQ_ * 2;   // 8 MB
    const size_t NEED = 2 * SZ_Q + 2 * SZ_K + SZ_K;    // 32 MB
    if (ws_size < NEED) {
        marker_kernel<<<(out_size + 255) / 256, 256, 0, stream>>>(
            (float*)d_out, out_size, (float)(ws_size >> 20));
        return;
    }

    char* ws = (char*)d_ws;
    u16* Qhi = (u16*)(ws);
    u16* Qlo = (u16*)(ws + SZ_Q);
    u16* Khi = (u16*)(ws + 2 * SZ_Q);
    u16* Klo = (u16*)(ws + 2 * SZ_Q + SZ_K);
    u16* Vb  = (u16*)(ws + 2 * SZ_Q + 2 * SZ_K);

    // weight-split scratch carved from regions dead at that moment.
    // K+V projections run in ONE launch, so WkT and WvT must both live
    // outside {Khi, Klo, Vb} — d_out (8 MB, dead until final GEMM) holds
    // WvT [0,3MB) + WkT [3,6MB). WqT stays in Khi (Q-proj, a separate earlier
    // launch, completes before gemm_kv writes Khi).
    u16* WqT_h = Khi;                      // Khi unwritten until K-proj
    u16* WqT_l = Khi + (size_t)DQ_ * DQ_;
    u16* WvT_h = (u16*)d_out;              // d_out dead until final GEMM
    u16* WvT_l = WvT_h + (size_t)DC_ * DQ_;
    u16* WkT_h = WvT_h + 2 * (size_t)DC_ * DQ_;
    u16* WkT_l = WvT_h + 3 * (size_t)DC_ * DQ_;
    u16* WoT_h = Khi;                      // Khi dead after attention
    u16* WoT_l = Khi + (size_t)DQ_ * DQ_;

    const int MQ = BN_ * TQ_;  // 2048
    const int MK = BN_ * TK_;  // 4096

    // Batched pre-attention weight transposes (Wq/Wk/Wv) in one launch;
    // grid y padded to max K/32 = 32, z selects the job.
    TsplitJob jq{Wq, WqT_h, WqT_l, DQ_, DQ_};
    TsplitJob jk{Wk, WkT_h, WkT_l, DC_, DQ_};
    TsplitJob jv{Wv, WvT_h, WvT_l, DC_, DQ_};
    tsplit3<<<dim3(DQ_ / 32, DQ_ / 32, 3), 256, 0, stream>>>(jq, jk, jv);

    // Q projection (scale DH^-0.5 folded into the hi/lo split); grid (8,32)
    gemm3<0, 2><<<dim3(DQ_ / 128, MQ / 64), 256, 0, stream>>>(
        x, nullptr, WqT_h, WqT_l, bq, 0.125f, Qhi, Qlo, MQ, DQ_, DQ_);

    // K + V projections batched in one launch; grid (8,64,2)
    GemmKVJob jobK{WkT_h, WkT_l, bk, Khi, Klo, 2};
    GemmKVJob jobV{WvT_h, WvT_l, bv, Vb, nullptr, 1};
    gemm_kv<<<dim3(DQ_ / 128, MK / 64, 2), 256, 0, stream>>>(
        ctx, jobK, jobV, MK, DQ_, DC_);

    // fused top-64 attention; writes attn hi/lo in place over Qhi/Qlo
    attn_topk<<<dim3(TQ_ / 16, NH_, BN_), 256, 0, stream>>>(
        Qhi, Qlo, Khi, Klo, Vb, msk, Qhi, Qlo);

    // output projection: split-A (attn hi/lo), fp32 out; grid (8,32)
    tsplit<<<dim3(DQ_ / 32, DQ_ / 32), 256, 0, stream>>>(Wo, WoT_h, WoT_l, DQ_, DQ_);
    gemm3<1, 0><<<dim3(DQ_ / 128, MQ / 64), 256, 0, stream>>>(
        Qhi, Qlo, WoT_h, WoT_l, bo, 1.0f, d_out, nullptr, MQ, DQ_, DQ_);
}

// Round 8
// 423.647 us; speedup vs baseline: 1.0551x; 1.0551x over previous
//
#include <hip/hip_runtime.h>
#include <hip/hip_bf16.h>
#include <cstdint>
#include <cstddef>

// Problem constants (from reference). Inputs/outputs are fp32 (verified round 4).
#define BN_ 2
#define TQ_ 1024
#define TK_ 2048
#define DQ_ 1024
#define DC_ 768
#define NH_ 16
#define DH_ 64
#define TOPK_ 64

typedef unsigned short u16;
typedef __attribute__((ext_vector_type(8))) short short8;   // 8 bf16 MFMA frag
typedef __attribute__((ext_vector_type(8))) u16   ushort8;  // 16B vector load
typedef __attribute__((ext_vector_type(4))) float floatx4;  // MFMA acc / float4

__device__ __forceinline__ float bf2f(u16 u) { return __uint_as_float(((unsigned)u) << 16); }
__device__ __forceinline__ u16 f2bf(float f) {  // round-to-nearest-even (manual)
    unsigned u = __float_as_uint(f);
    u += 0x7FFFu + ((u >> 16) & 1u);
    return (u16)(u >> 16);
}
// HW-converter variant for hot staging loops: compiler emits v_cvt_pk_bf16_f32
// pairs (m240: scalar cast beats hand asm). RNE == RNE -> bit-identical to
// f2bf for all non-NaN inputs (ours are definite).
__device__ __forceinline__ u16 f2bf_cvt(float f) {
    union { __hip_bfloat16 b; u16 u; } cv;
    cv.b = __float2bfloat16(f);
    return cv.u;
}
__device__ __forceinline__ float definite(float v, float repl) {
    return ((__float_as_uint(v) & 0x7F800000u) == 0x7F800000u) ? repl : v;
}
// monotone float<->uint mapping (ascending)
__device__ __forceinline__ unsigned mono(float f) {
    unsigned u = __float_as_uint(f);
    return (u & 0x80000000u) ? ~u : (u | 0x80000000u);
}
__device__ __forceinline__ float invmono(unsigned u) {
    return __uint_as_float((u & 0x80000000u) ? (u & 0x7FFFFFFFu) : ~u);
}
// async global(16B) -> LDS direct copy. LDS dest must be linear in lane
// (base + lane*16); the swizzle lives in the per-lane GLOBAL address
// (m173 pattern: linear LDS dest + pre-swizzled per-lane source).
__device__ __forceinline__ void gld16(const u16* g, u16* l) {
    __builtin_amdgcn_global_load_lds(
        (const __attribute__((address_space(1))) unsigned*)g,
        (__attribute__((address_space(3))) unsigned*)l, 16, 0, 0);
}
// 16-lane-group reductions (xor offsets 1,2,4,8 stay inside row-of-16 -> DPP)
__device__ __forceinline__ int gsum16(int x) {
#pragma unroll
    for (int o = 1; o < 16; o <<= 1) x += __shfl_xor(x, o);
    return x;
}
__device__ __forceinline__ int gmin16(int x) {
#pragma unroll
    for (int o = 1; o < 16; o <<= 1) { int y = __shfl_xor(x, o); x = (y < x) ? y : x; }
    return x;
}
__device__ __forceinline__ unsigned gmin16u(unsigned x) {
#pragma unroll
    for (int o = 1; o < 16; o <<= 1) { unsigned y = __shfl_xor((int)x, o); x = (y < x) ? y : x; }
    return x;
}
__device__ __forceinline__ unsigned gmax16u(unsigned x) {
#pragma unroll
    for (int o = 1; o < 16; o <<= 1) { unsigned y = __shfl_xor((int)x, o); x = (y > x) ? y : x; }
    return x;
}
__device__ __forceinline__ float gmax16f(float x) {
#pragma unroll
    for (int o = 1; o < 16; o <<= 1) x = fmaxf(x, __shfl_xor(x, o));
    return x;
}
__device__ __forceinline__ float gsum16f(float x) {
#pragma unroll
    for (int o = 1; o < 16; o <<= 1) x += __shfl_xor(x, o);
    return x;
}
// LDS bank-conflict swizzle for the qtr0 logit region.
// Targets: logit STORES (rows quad*4+r) and um LOADS (rows wave*4+quad);
// row stride 512 dwords is bank-invariant -> both were 4-way conflicts.
// XOR is a bijection; um[j] still holds key (l16+16j)'s logit -> select
// bit-identical. r21 measured: conflicts 6.6M->5.6M (kept; residual lives
// in the unswizzled compact-select/carry phases).
__device__ __forceinline__ int lgswz(int row) {
    return ((((row >> 2) ^ row) & 1) << 4) | (((row >> 1) & 1) << 2);
}

// diagnostic: fill output with a recognizable constant (fp32 out)
__global__ void marker_kernel(float* __restrict__ out, int n, float val) {
    const int i = blockIdx.x * 256 + threadIdx.x;
    if (i < n) out[i] = val;
}

// ---------------------------------------------------------------------------
// Exact top-64 selection, qtr0 variant: 32 values/lane with IMPLICIT keys
// key(j) = (l16 + 16*j) << 11 (pre-scaled V byte offset, affine in register
// index j — no kk[32] array, which was the residual spill source at 64 VGPR).
// Early-exit when count==64 ({u >= X} exactly 64). Compact >X then tie-fill
// ==X ascending-key. Returns xval = invmono(X) (lower bound on kept min).
__device__ __forceinline__ float select_topk32_ik(const unsigned (&um)[32], int l16,
                                                  float* cvrow, int* ckrow) {
    unsigned X = 0u;
    bool done = false;
    for (int bit = 31; bit >= 0; --bit) {
        const unsigned C = X | (1u << bit);
        int c = 0;
#pragma unroll
        for (int j = 0; j < 32; ++j) c += (um[j] >= C) ? 1 : 0;
        c = gsum16(c);
        if (!done && c >= 64) X = C;
        if (c == 64) done = true;
        if (__all(done)) break;
    }
    // compact strictly-greater
    int myGt = 0;
#pragma unroll
    for (int j = 0; j < 32; ++j) myGt += (um[j] > X) ? 1 : 0;
    const int totalGt = gsum16(myGt);
    int pre = myGt;
#pragma unroll
    for (int off = 1; off < 16; off <<= 1) {
        const int tv = __shfl_up(pre, off);
        if (l16 >= off) pre += tv;
    }
    int wpos = pre - myGt;
#pragma unroll
    for (int j = 0; j < 32; ++j) {
        if (um[j] > X) {
            cvrow[wpos] = invmono(um[j]);
            ckrow[wpos] = (l16 + 16 * j) << 11;
            ++wpos;
        }
    }
    // tie-fill remaining slots with ==X entries, ascending key
    const float xval = invmono(X);
    int remaining = 64 - totalGt;
    int pos = totalGt;
    int lastkey = -1;
    while (remaining > 0) {
        int mykey = 0x7FFFFFFF;
#pragma unroll
        for (int j = 0; j < 32; ++j) {
            const int kj = (l16 + 16 * j) << 11;
            if (um[j] == X && kj > lastkey && kj < mykey) mykey = kj;
        }
        const int mn = gmin16(mykey);
        if (mn == 0x7FFFFFFF) break;
        if (mykey == mn) { cvrow[pos] = xval; ckrow[pos] = mn; }
        lastkey = mn;
        ++pos; --remaining;
    }
    return xval;
}

// ---------------------------------------------------------------------------
// Compact-phase select: NV values/lane (explicit scaled keys), z-space vs
// base. Same algorithm; writes separate value/key arrays.
template <int NV>
__device__ __forceinline__ float select_topk(const unsigned (&um)[NV], const int (&kk)[NV],
                                             unsigned base, int hb, int l16,
                                             float* cvrow, int* ckrow) {
    unsigned X = 0u;
    bool done = false;
    for (int bit = hb; bit >= 0; --bit) {
        const unsigned C = X | (1u << bit);
        int c = 0;
#pragma unroll
        for (int j = 0; j < NV; ++j) c += (um[j] >= C) ? 1 : 0;
        c = gsum16(c);
        if (!done && c >= 64) X = C;
        if (c == 64) done = true;
        if (__all(done)) break;
    }
    int myGt = 0;
#pragma unroll
    for (int j = 0; j < NV; ++j) myGt += (um[j] > X) ? 1 : 0;
    const int totalGt = gsum16(myGt);
    int pre = myGt;
#pragma unroll
    for (int off = 1; off < 16; off <<= 1) {
        const int tv = __shfl_up(pre, off);
        if (l16 >= off) pre += tv;
    }
    int wpos = pre - myGt;
#pragma unroll
    for (int j = 0; j < NV; ++j) {
        if (um[j] > X) {
            cvrow[wpos] = invmono(base + um[j]);
            ckrow[wpos] = kk[j];
            ++wpos;
        }
    }
    const float xval = invmono(base + X);
    int remaining = 64 - totalGt;
    int pos = totalGt;
    int lastkey = -1;
    while (remaining > 0) {
        int mykey = 0x7FFFFFFF;
#pragma unroll
        for (int j = 0; j < NV; ++j)
            if (um[j] == X && kk[j] > lastkey && kk[j] < mykey) mykey = kk[j];
        const int mn = gmin16(mykey);
        if (mn == 0x7FFFFFFF) break;
        if (mykey == mn) { cvrow[pos] = xval; ckrow[pos] = mn; }
        lastkey = mn;
        ++pos; --remaining;
    }
    return xval;
}

// ---------------------------------------------------------------------------
// Transpose + hi/lo-split: W fp32 [K][N] -> Wh,Wl bf16 [N][K]
// Batched variant: blockIdx.z selects among up to 3 independent weights
// (saves 2 kernel launches + stream bubbles vs separate dispatches).
struct TsplitJob { const float* W; u16* Wh; u16* Wl; int K; int N; };

__global__ void __launch_bounds__(256) tsplit3(TsplitJob j0, TsplitJob j1, TsplitJob j2) {
    const TsplitJob j = (blockIdx.z == 0) ? j0 : (blockIdx.z == 1) ? j1 : j2;
    const int bk = blockIdx.y * 32;
    if (bk >= j.K) return;                      // grids padded to max K/32
    __shared__ float t[32][33];
    const int x = threadIdx.x & 31, y = threadIdx.x >> 5;   // y in 0..7
    const int bn = blockIdx.x * 32;
#pragma unroll
    for (int i = 0; i < 32; i += 8) t[y + i][x] = j.W[(size_t)(bk + y + i) * j.N + bn + x];
    __syncthreads();
#pragma unroll
    for (int i = 0; i < 32; i += 8) {
        const float f = t[x][y + i];            // = W[bk+x][bn+y+i]
        const u16 hi = f2bf(f);
        const size_t o = (size_t)(bn + y + i) * j.K + bk + x;
        j.Wh[o] = hi;
        j.Wl[o] = f2bf(f - bf2f(hi));
    }
}

__global__ void __launch_bounds__(256) tsplit(const float* __restrict__ W,
                                              u16* __restrict__ Wh, u16* __restrict__ Wl,
                                              int K, int N) {
    __shared__ float t[32][33];
    const int x = threadIdx.x & 31, y = threadIdx.x >> 5;
    const int bn = blockIdx.x * 32, bk = blockIdx.y * 32;
#pragma unroll
    for (int i = 0; i < 32; i += 8) t[y + i][x] = W[(size_t)(bk + y + i) * N + bn + x];
    __syncthreads();
#pragma unroll
    for (int i = 0; i < 32; i += 8) {
        const float f = t[x][y + i];
        const u16 hi = f2bf(f);
        const size_t o = (size_t)(bn + y + i) * K + bk + x;
        Wh[o] = hi;
        Wl[o] = f2bf(f - bf2f(hi));
    }
}

// ---------------------------------------------------------------------------
// GEMM (round-11 proven structure; r19: global_load_lds staging for pre-split
// operands; r21: A-split conversion via HW cvt (v_cvt_pk_bf16_f32) — RNE
// bit-identical to manual f2bf, fewer VALU ops in the hot staging loop).
// C[M][N] = A[M][K] * W[K][N] + bias, * scale.
// B pre-transposed & split: Bh/Bl bf16 [N][K]. Tile 64(M) x 128(N), BK=64.
// XOR-swizzled UNPADDED LDS: row m chunk c stored at slot m*8 + (c ^ (m&7)).
// 4 waves 2x2: wave tile 32(m) x 64(n) = 2x4 mfma_16x16x32, 3-term split
// (ah*bh + al*bh + ah*bl). LDS 48KB -> 3 WG/CU.
// ASPLIT 0: A fp32 (split at stage). ASPLIT 1: A bf16 hi/lo (global_load_lds).
// OMODE 0: fp32 out. 1: bf16 out. 2: hi/lo pair out.
template <int ASPLIT, int OMODE>
__global__ void __launch_bounds__(256) gemm3(
    const void* __restrict__ Ap, const void* __restrict__ Alp,
    const u16* __restrict__ Bh, const u16* __restrict__ Bl,
    const float* __restrict__ bias, float scale,
    void* __restrict__ out0, void* __restrict__ out1,
    int M, int N, int K) {
    __shared__ u16 Ahs[64 * 64];    // 8 KB   [m][k] hi, swizzled
    __shared__ u16 Als[64 * 64];    // 8 KB   lo
    __shared__ u16 Bhs[128 * 64];   // 16 KB  [n][k] hi, swizzled
    __shared__ u16 Bls[128 * 64];   // 16 KB  lo

    const int tid = threadIdx.x;
    const int lane = tid & 63, wave = tid >> 6;
    const int wm = wave >> 1, wn = wave & 1;
    const int quad = lane >> 4, l16 = lane & 15;
    const int bm = blockIdx.y * 64, bn = blockIdx.x * 128;

    floatx4 acc[2][4] = {};

    for (int k0 = 0; k0 < K; k0 += 64) {
        __syncthreads();
        // ---- stage A: 64 rows x 64 cols = 512 slots of 8 elems, 2 per thread
#pragma unroll
        for (int s2 = 0; s2 < 2; ++s2) {
            const int slot = tid + s2 * 256;
            const int m = slot >> 3, cpos = slot & 7;
            const int c = cpos ^ (m & 7);
            const size_t aoff = (size_t)(bm + m) * K + k0 + c * 8;
            if constexpr (ASPLIT == 0) {
                const float* f = (const float*)Ap + aoff;
                const floatx4 a = *(const floatx4*)f;
                const floatx4 b = *(const floatx4*)(f + 4);
                ushort8 hi, lo;
#pragma unroll
                for (int j = 0; j < 4; ++j) {
                    const u16 t = f2bf_cvt(a[j]);
                    hi[j] = t; lo[j] = f2bf_cvt(a[j] - bf2f(t));
                    const u16 t2 = f2bf_cvt(b[j]);
                    hi[4 + j] = t2; lo[4 + j] = f2bf_cvt(b[j] - bf2f(t2));
                }
                *(ushort8*)&Ahs[slot * 8] = hi;
                *(ushort8*)&Als[slot * 8] = lo;
            } else {
                gld16((const u16*)Ap  + aoff, &Ahs[slot * 8]);
                gld16((const u16*)Alp + aoff, &Als[slot * 8]);
            }
        }
        // ---- stage B: 128 rows x 64 cols = 1024 slots, 4 per thread,
        //      async direct-to-LDS (dest linear in lane; swizzle in gaddr)
#pragma unroll
        for (int s4 = 0; s4 < 4; ++s4) {
            const int slot = tid + s4 * 256;
            const int n = slot >> 3, cpos = slot & 7;
            const int c = cpos ^ (n & 7);
            const size_t boff = (size_t)(bn + n) * K + k0 + c * 8;
            gld16(Bh + boff, &Bhs[slot * 8]);
            gld16(Bl + boff, &Bls[slot * 8]);
        }
        __syncthreads();
#pragma unroll
        for (int s = 0; s < 2; ++s) {
            short8 ah[2], al[2], bh[4], bl[4];
#pragma unroll
            for (int mt = 0; mt < 2; ++mt) {
                const int m = wm * 32 + mt * 16 + l16;
                const int cs = s * 4 + quad;
                const int slot = m * 8 + (cs ^ (m & 7));
                ah[mt] = *(const short8*)&Ahs[slot * 8];
                al[mt] = *(const short8*)&Als[slot * 8];
            }
#pragma unroll
            for (int nt = 0; nt < 4; ++nt) {
                const int n = wn * 64 + nt * 16 + l16;
                const int cs = s * 4 + quad;
                const int slot = n * 8 + (cs ^ (n & 7));
                bh[nt] = *(const short8*)&Bhs[slot * 8];
                bl[nt] = *(const short8*)&Bls[slot * 8];
            }
#pragma unroll
            for (int mt = 0; mt < 2; ++mt)
#pragma unroll
                for (int nt = 0; nt < 4; ++nt) {
                    acc[mt][nt] = __builtin_amdgcn_mfma_f32_16x16x32_bf16(ah[mt], bh[nt], acc[mt][nt], 0, 0, 0);
                    acc[mt][nt] = __builtin_amdgcn_mfma_f32_16x16x32_bf16(al[mt], bh[nt], acc[mt][nt], 0, 0, 0);
                    acc[mt][nt] = __builtin_amdgcn_mfma_f32_16x16x32_bf16(ah[mt], bl[nt], acc[mt][nt], 0, 0, 0);
                }
        }
    }

#pragma unroll
    for (int mt = 0; mt < 2; ++mt) {
#pragma unroll
        for (int nt = 0; nt < 4; ++nt) {
            const int col = bn + wn * 64 + nt * 16 + l16;
            const float bcol = bias[col];
#pragma unroll
            for (int r = 0; r < 4; ++r) {
                const int row = bm + wm * 32 + mt * 16 + quad * 4 + r;
                const float val = definite((acc[mt][nt][r] + bcol) * scale, 0.0f);
                const size_t idx = (size_t)row * N + col;
                if constexpr (OMODE == 0) {
                    ((float*)out0)[idx] = val;
                } else if constexpr (OMODE == 1) {
                    ((u16*)out0)[idx] = f2bf(val);
                } else {
                    const u16 hi = f2bf(val);
                    ((u16*)out0)[idx] = hi;
                    ((u16*)out1)[idx] = f2bf(val - bf2f(hi));
                }
            }
        }
    }
}

// ---------------------------------------------------------------------------
// Batched K+V projection: one launch, blockIdx.z selects the job. Both jobs
// share A = ctx (fp32, split at stage with HW cvt), M, N, K; differ in
// B/bias/out/omode. NOTE: WkT/WvT live in d_out (dead until final GEMM).
struct GemmKVJob { const u16* Bh; const u16* Bl; const float* bias;
                   void* out0; void* out1; int omode; };

__global__ void __launch_bounds__(256) gemm_kv(
    const float* __restrict__ Ap, GemmKVJob j0, GemmKVJob j1,
    int M, int N, int K) {
    const GemmKVJob j = (blockIdx.z == 0) ? j0 : j1;
    __shared__ u16 Ahs[64 * 64];
    __shared__ u16 Als[64 * 64];
    __shared__ u16 Bhs[128 * 64];
    __shared__ u16 Bls[128 * 64];

    const int tid = threadIdx.x;
    const int lane = tid & 63, wave = tid >> 6;
    const int wm = wave >> 1, wn = wave & 1;
    const int quad = lane >> 4, l16 = lane & 15;
    const int bm = blockIdx.y * 64, bn = blockIdx.x * 128;

    floatx4 acc[2][4] = {};

    for (int k0 = 0; k0 < K; k0 += 64) {
        __syncthreads();
#pragma unroll
        for (int s2 = 0; s2 < 2; ++s2) {
            const int slot = tid + s2 * 256;
            const int m = slot >> 3, cpos = slot & 7;
            const int c = cpos ^ (m & 7);
            const size_t aoff = (size_t)(bm + m) * K + k0 + c * 8;
            const float* f = Ap + aoff;
            const floatx4 a = *(const floatx4*)f;
            const floatx4 b = *(const floatx4*)(f + 4);
            ushort8 hi, lo;
#pragma unroll
            for (int jj = 0; jj < 4; ++jj) {
                const u16 t = f2bf_cvt(a[jj]);
                hi[jj] = t; lo[jj] = f2bf_cvt(a[jj] - bf2f(t));
                const u16 t2 = f2bf_cvt(b[jj]);
                hi[4 + jj] = t2; lo[4 + jj] = f2bf_cvt(b[jj] - bf2f(t2));
            }
            *(ushort8*)&Ahs[slot * 8] = hi;
            *(ushort8*)&Als[slot * 8] = lo;
        }
#pragma unroll
        for (int s4 = 0; s4 < 4; ++s4) {
            const int slot = tid + s4 * 256;
            const int n = slot >> 3, cpos = slot & 7;
            const int c = cpos ^ (n & 7);
            const size_t boff = (size_t)(bn + n) * K + k0 + c * 8;
            gld16(j.Bh + boff, &Bhs[slot * 8]);
            gld16(j.Bl + boff, &Bls[slot * 8]);
        }
        __syncthreads();
#pragma unroll
        for (int s = 0; s < 2; ++s) {
            short8 ah[2], al[2], bh[4], bl[4];
#pragma unroll
            for (int mt = 0; mt < 2; ++mt) {
                const int m = wm * 32 + mt * 16 + l16;
                const int cs = s * 4 + quad;
                const int slot = m * 8 + (cs ^ (m & 7));
                ah[mt] = *(const short8*)&Ahs[slot * 8];
                al[mt] = *(const short8*)&Als[slot * 8];
            }
#pragma unroll
            for (int nt = 0; nt < 4; ++nt) {
                const int n = wn * 64 + nt * 16 + l16;
                const int cs = s * 4 + quad;
                const int slot = n * 8 + (cs ^ (n & 7));
                bh[nt] = *(const short8*)&Bhs[slot * 8];
                bl[nt] = *(const short8*)&Bls[slot * 8];
            }
#pragma unroll
            for (int mt = 0; mt < 2; ++mt)
#pragma unroll
                for (int nt = 0; nt < 4; ++nt) {
                    acc[mt][nt] = __builtin_amdgcn_mfma_f32_16x16x32_bf16(ah[mt], bh[nt], acc[mt][nt], 0, 0, 0);
                    acc[mt][nt] = __builtin_amdgcn_mfma_f32_16x16x32_bf16(al[mt], bh[nt], acc[mt][nt], 0, 0, 0);
                    acc[mt][nt] = __builtin_amdgcn_mfma_f32_16x16x32_bf16(ah[mt], bl[nt], acc[mt][nt], 0, 0, 0);
                }
        }
    }

#pragma unroll
    for (int mt = 0; mt < 2; ++mt) {
#pragma unroll
        for (int nt = 0; nt < 4; ++nt) {
            const int col = bn + wn * 64 + nt * 16 + l16;
            const float bcol = j.bias[col];
#pragma unroll
            for (int r = 0; r < 4; ++r) {
                const int row = bm + wm * 32 + mt * 16 + quad * 4 + r;
                const float val = definite(acc[mt][nt][r] + bcol, 0.0f);
                const size_t idx = (size_t)row * N + col;
                if (j.omode == 1) {
                    ((u16*)j.out0)[idx] = f2bf(val);
                } else {
                    const u16 hi = f2bf(val);
                    ((u16*)j.out0)[idx] = hi;
                    ((u16*)j.out1)[idx] = f2bf(val - bf2f(hi));
                }
            }
        }
    }
}

// ---------------------------------------------------------------------------
// Fused attention (round-22: REVERT r21's XCD block swizzle; keep lgswz).
// Cross-round ledger (attn us / occ% / WRITE MB / FETCH MB / conflicts):
//   r18 safe cuts:            218 / 43 / 16  / 105 / 6.6M
//   r20 32768 LDS, zero spill:215.6/ 43 / 8  / 100 / 6.6M
//   r21 +lgswz +XCD swizzle:  258 / 43 / 187 / 67  / 5.6M  <- WRITE x23!
// r21 lesson: XCD swizzle fixed read locality (-33MB FETCH) but destroyed
// the in-place output's L2 write coalescing: original mapping put all 16
// h-writers of a q-row on ONE XCD (flat ids 64 apart, 64%8==0); swizzle
// spread them over 4 XCDs -> partial-row evictions, WRITE 8->187MB, +42us.
// Write locality of the default mapping is load-bearing — do NOT block-swizzle
// this kernel while outputs are in-place 128B row segments.
// lgswz kept: harmless, conflicts 6.6->5.6M (residual is in the unswizzled
// compact-select/carry phases — next target is the serial bit-search chain).
__global__ void __launch_bounds__(256, 4) attn_topk(
    const u16* Qhi, const u16* Qlo,     // aliased with outputs - no __restrict__
    const u16* __restrict__ Khi, const u16* __restrict__ Klo,
    const u16* __restrict__ Vb16, const void* __restrict__ maskp,
    u16* attnH, u16* attnL) {
    __shared__ float lg[16][512];     // 32768 B total (carry aliased inside)

#define CV_(row) (&lg[row][256])
#define CK_(row) (((int*)&lg[row][0]) + 320)

    const int tid = threadIdx.x;
    const int lane = tid & 63, wave = tid >> 6;
    const int quad = lane >> 4, l16 = lane & 15;
    const int rowg = wave * 4 + quad;              // this lane's selection row
    const int b = blockIdx.z, h = blockIdx.y, q0 = blockIdx.x * 16;
    const int sRow = lgswz(rowg);                  // this lane's um-load swizzle

    // ---- mask dtype probe: per-wave, barrier-free (first 1024 u16 = 2 KB)
    int mmode;
    {
        bool cbyte = false, cbf = false, cf32 = false;
#pragma unroll
        for (int j = 0; j < 16; ++j) {
            const int i = lane + 64 * j;
            const unsigned v = ((const u16*)maskp)[i];
            cbyte |= (v == 0x0100u || v == 0x0101u) || ((i & 1) && v == 0x0001u);
            cbf   |= (!(i & 1)) && v == 0x3F80u;
            cf32  |= (i & 1) && v == 0x3F80u;
        }
        const bool abf = __any(cbf), af32 = __any(cf32), abyte = __any(cbyte);
        mmode = abf ? 2 : (af32 ? 3 : (abyte ? 1 : 0));
    }

    // ---- Q fragments (A-operand: m=lane&15, k=quad*8+j), two k-steps of 32
    short8 qh[2], ql[2];
    {
        const size_t base = (size_t)(b * TQ_ + q0 + l16) * DQ_ + h * DH_ + quad * 8;
        qh[0] = *(const short8*)(Qhi + base);
        qh[1] = *(const short8*)(Qhi + base + 32);
        ql[0] = *(const short8*)(Qlo + base);
        ql[1] = *(const short8*)(Qlo + base + 32);
    }

    for (int qtr = 0; qtr < 4; ++qtr) {
        if (qtr == 0) {
            // ---- full logit phase: write all 512 per row (bank-swizzled)
#pragma unroll 2
            for (int t = 0; t < 8; ++t) {
                const int key = wave * 128 + t * 16 + l16;
                const size_t kb = (size_t)(b * TK_ + key) * DQ_ + h * DH_ + quad * 8;
                const short8 kh0 = *(const short8*)(Khi + kb);
                const short8 kh1 = *(const short8*)(Khi + kb + 32);
                const short8 kl0 = *(const short8*)(Klo + kb);
                const short8 kl1 = *(const short8*)(Klo + kb + 32);
                floatx4 acc = {};
                acc = __builtin_amdgcn_mfma_f32_16x16x32_bf16(qh[0], kh0, acc, 0, 0, 0);
                acc = __builtin_amdgcn_mfma_f32_16x16x32_bf16(ql[0], kh0, acc, 0, 0, 0);
                acc = __builtin_amdgcn_mfma_f32_16x16x32_bf16(qh[0], kl0, acc, 0, 0, 0);
                acc = __builtin_amdgcn_mfma_f32_16x16x32_bf16(qh[1], kh1, acc, 0, 0, 0);
                acc = __builtin_amdgcn_mfma_f32_16x16x32_bf16(ql[1], kh1, acc, 0, 0, 0);
                acc = __builtin_amdgcn_mfma_f32_16x16x32_bf16(qh[1], kl1, acc, 0, 0, 0);
                const int midx = b * TK_ + key;
                bool masked;
                if (mmode == 2)      masked = ((const u16*)maskp)[midx] != 0;
                else if (mmode == 3) masked = ((const float*)maskp)[midx] != 0.0f;
                else if (mmode == 1) masked = ((const unsigned char*)maskp)[midx] != 0;
                else                 masked = ((const int*)maskp)[midx] != 0;
#pragma unroll
                for (int r = 0; r < 4; ++r) {
                    const int row = quad * 4 + r;
                    lg[row][key ^ lgswz(row)] = masked ? -3.0e38f : acc[r];
                }
            }
            __syncthreads();

            // ---- full select over 32 new values, implicit keys (carry is
            // -inf in qtr0 and provably never selected: every logit >= -3e38)
            unsigned um[32];
#pragma unroll
            for (int j = 0; j < 32; ++j)
                um[j] = mono(lg[rowg][(l16 + 16 * j) ^ sRow]);
            const float th = select_topk32_ik(um, l16, CV_(rowg), CK_(rowg));
            if (l16 == 0) {
                lg[rowg][255] = th;                 // filter threshold for next qtr
                ((int*)&lg[rowg][0])[511] = 0;      // reset candidate counter
            }
        } else {
            // ---- filtered logit phase: push only survivors (> th) compactly
            float cmrow[4];
#pragma unroll
            for (int r = 0; r < 4; ++r) cmrow[r] = lg[quad * 4 + r][255];
#pragma unroll 2
            for (int t = 0; t < 8; ++t) {
                const int key = qtr * 512 + wave * 128 + t * 16 + l16;
                const size_t kb = (size_t)(b * TK_ + key) * DQ_ + h * DH_ + quad * 8;
                const short8 kh0 = *(const short8*)(Khi + kb);
                const short8 kh1 = *(const short8*)(Khi + kb + 32);
                const short8 kl0 = *(const short8*)(Klo + kb);
                const short8 kl1 = *(const short8*)(Klo + kb + 32);
                floatx4 acc = {};
                acc = __builtin_amdgcn_mfma_f32_16x16x32_bf16(qh[0], kh0, acc, 0, 0, 0);
                acc = __builtin_amdgcn_mfma_f32_16x16x32_bf16(ql[0], kh0, acc, 0, 0, 0);
                acc = __builtin_amdgcn_mfma_f32_16x16x32_bf16(qh[0], kl0, acc, 0, 0, 0);
                acc = __builtin_amdgcn_mfma_f32_16x16x32_bf16(qh[1], kh1, acc, 0, 0, 0);
                acc = __builtin_amdgcn_mfma_f32_16x16x32_bf16(ql[1], kh1, acc, 0, 0, 0);
                acc = __builtin_amdgcn_mfma_f32_16x16x32_bf16(qh[1], kl1, acc, 0, 0, 0);
                const int midx = b * TK_ + key;
                bool masked;
                if (mmode == 2)      masked = ((const u16*)maskp)[midx] != 0;
                else if (mmode == 3) masked = ((const float*)maskp)[midx] != 0.0f;
                else if (mmode == 1) masked = ((const unsigned char*)maskp)[midx] != 0;
                else                 masked = ((const int*)maskp)[midx] != 0;
#pragma unroll
                for (int r = 0; r < 4; ++r) {
                    const float val = masked ? -3.0e38f : acc[r];
                    if (val > cmrow[r]) {
                        const int row = quad * 4 + r;
                        const int pos = atomicAdd((int*)&lg[row][511], 1);
                        if (pos < 127) {
                            lg[row][pos] = val;
                            ((int*)&lg[row][0])[128 + pos] = key << 11;
                        }
                    }
                }
            }
            __syncthreads();

            // ---- compact select: 8 candidates + 4 carry per lane, z-space
            unsigned uc[4]; int ck4[4];
#pragma unroll
            for (int t = 0; t < 4; ++t) {
                uc[t] = mono(CV_(rowg)[l16 + 16 * t]);
                ck4[t] = CK_(rowg)[l16 + 16 * t];
            }
            unsigned cm = uc[0];
            cm = (uc[1] < cm) ? uc[1] : cm;
            cm = (uc[2] < cm) ? uc[2] : cm;
            cm = (uc[3] < cm) ? uc[3] : cm;
            cm = gmin16u(cm);
            int cnt = ((int*)&lg[rowg][0])[511];
            if (cnt > 127) cnt = 127;

            unsigned zm[12]; int kk[12];
            unsigned zmx = 0;
#pragma unroll
            for (int i = 0; i < 8; ++i) {
                const int idx = l16 + 16 * i;          // 0..127
                const bool valid = idx < cnt;
                const float v = lg[rowg][idx];
                const int k = ((int*)&lg[rowg][0])[128 + idx];
                const unsigned mv = mono(v);
                // CLAMP: th (early-exit X) can sit below the true carry-min cm;
                // mv <= cm candidates can never be in the exact top-64 -> pads.
                const bool live = valid && (mv > cm);
                zm[i] = live ? (mv - cm) : 0u;
                kk[i] = live ? k : 0x7FFFFFFF;
                zmx = (zm[i] > zmx) ? zm[i] : zmx;
            }
#pragma unroll
            for (int t = 0; t < 4; ++t) {
                zm[8 + t] = uc[t] - cm;
                kk[8 + t] = ck4[t];
                zmx = (zm[8 + t] > zmx) ? zm[8 + t] : zmx;
            }
            zmx = gmax16u(zmx);
            const int hb = 31 - __clz(zmx | 1u);
            const float th = select_topk<12>(zm, kk, cm, hb, l16, CV_(rowg), CK_(rowg));
            if (l16 == 0) {
                lg[rowg][255] = th;
                ((int*)&lg[rowg][0])[511] = 0;
            }
        }
        if (qtr < 3) __syncthreads();   // th/counter + lg reuse next quarter
    }

    // ---- softmax over 64 kept entries (group-parallel; same-wave LDS ordering)
    {
        float v4[4];
#pragma unroll
        for (int t = 0; t < 4; ++t) v4[t] = CV_(rowg)[l16 + 16 * t];
        float m = fmaxf(fmaxf(v4[0], v4[1]), fmaxf(v4[2], v4[3]));
        m = gmax16f(m);
        float p4[4], S = 0.f;
#pragma unroll
        for (int t = 0; t < 4; ++t) { p4[t] = __expf(v4[t] - m); S += p4[t]; }
        S = gsum16f(S);
        const float inv = 1.0f / S;
#pragma unroll
        for (int t = 0; t < 4; ++t) CV_(rowg)[l16 + 16 * t] = p4[t] * inv;
    }

    // ---- weighted bf16-V gather: row-pairs, dword loads (2 dims/lane).
    // Carry keys are pre-scaled V byte offsets -> no per-entry 64-bit
    // multiply; bf16 unpack is 1 shl + 1 and.
    const int half = lane >> 5, l32 = lane & 31;
    const char* Vrow = (const char*)(Vb16 + (size_t)b * TK_ * DQ_ + h * DH_ + l32 * 2);
#pragma unroll
    for (int rp = 0; rp < 2; ++rp) {
        const int row = wave * 4 + rp * 2 + half;
        float a0 = 0.f, a1 = 0.f;
#pragma unroll 4
        for (int e = 0; e < 64; ++e) {
            const float w = CV_(row)[e];
            const int koff = CK_(row)[e];
            const unsigned v2 = *(const unsigned*)(Vrow + koff);
            a0 = fmaf(w, __uint_as_float(v2 << 16), a0);
            a1 = fmaf(w, __uint_as_float(v2 & 0xFFFF0000u), a1);
        }
        a0 = definite(a0, 0.0f);
        a1 = definite(a1, 0.0f);
        const size_t o = (size_t)(b * TQ_ + q0 + row) * DQ_ + h * DH_ + l32 * 2;
        const u16 h0 = f2bf(a0), h1 = f2bf(a1);
        const u16 l0 = f2bf(a0 - bf2f(h0)), l1 = f2bf(a1 - bf2f(h1));
        *(unsigned*)(attnH + o) = (unsigned)h0 | ((unsigned)h1 << 16);
        *(unsigned*)(attnL + o) = (unsigned)l0 | ((unsigned)l1 << 16);
    }
#undef CV_
#undef CK_
}

// ---------------------------------------------------------------------------
extern "C" void kernel_launch(void* const* d_in, const int* in_sizes, int n_in,
                              void* d_out, int out_size, void* d_ws, size_t ws_size,
                              hipStream_t stream) {
    static const int exp_sizes[11] = {2097152, 3145728, 4096, 1048576, 1024,
                                      786432, 1024, 786432, 1024, 1048576, 1024};
    if (n_in != 11) {
        marker_kernel<<<(out_size + 255) / 256, 256, 0, stream>>>((float*)d_out, out_size,
                                                                  (float)(150 + n_in));
        return;
    }
    for (int i = 0; i < 11; ++i)
        if (in_sizes[i] != exp_sizes[i]) {
            marker_kernel<<<(out_size + 255) / 256, 256, 0, stream>>>((float*)d_out, out_size,
                                                                      (float)(200 + i));
            return;
        }

    const float* x   = (const float*)d_in[0];
    const float* ctx = (const float*)d_in[1];
    const void*  msk = d_in[2];
    const float* Wq = (const float*)d_in[3];
    const float* bq = (const float*)d_in[4];
    const float* Wk = (const float*)d_in[5];
    const float* bk = (const float*)d_in[6];
    const float* Wv = (const float*)d_in[7];
    const float* bv = (const float*)d_in[8];
    const float* Wo = (const float*)d_in[9];
    const float* bo = (const float*)d_in[10];

    // ---- workspace: exactly 32 MB (verified sufficient)
    const size_t SZ_Q = (size_t)BN_ * TQ_ * DQ_ * 2;   // 4 MB
    const size_t SZ_K = (size_t)BN_ * TK_ * DQ_ * 2;   // 8 MB
    const size_t NEED = 2 * SZ_Q + 2 * SZ_K + SZ_K;    // 32 MB
    if (ws_size < NEED) {
        marker_kernel<<<(out_size + 255) / 256, 256, 0, stream>>>(
            (float*)d_out, out_size, (float)(ws_size >> 20));
        return;
    }

    char* ws = (char*)d_ws;
    u16* Qhi = (u16*)(ws);
    u16* Qlo = (u16*)(ws + SZ_Q);
    u16* Khi = (u16*)(ws + 2 * SZ_Q);
    u16* Klo = (u16*)(ws + 2 * SZ_Q + SZ_K);
    u16* Vb  = (u16*)(ws + 2 * SZ_Q + 2 * SZ_K);

    // weight-split scratch carved from regions dead at that moment.
    // K+V projections run in ONE launch, so WkT and WvT must both live
    // outside {Khi, Klo, Vb} — d_out (8 MB, dead until final GEMM) holds
    // WvT [0,3MB) + WkT [3,6MB). WqT stays in Khi (Q-proj, a separate earlier
    // launch, completes before gemm_kv writes Khi).
    u16* WqT_h = Khi;                      // Khi unwritten until K-proj
    u16* WqT_l = Khi + (size_t)DQ_ * DQ_;
    u16* WvT_h = (u16*)d_out;              // d_out dead until final GEMM
    u16* WvT_l = WvT_h + (size_t)DC_ * DQ_;
    u16* WkT_h = WvT_h + 2 * (size_t)DC_ * DQ_;
    u16* WkT_l = WvT_h + 3 * (size_t)DC_ * DQ_;
    u16* WoT_h = Khi;                      // Khi dead after attention
    u16* WoT_l = Khi + (size_t)DQ_ * DQ_;

    const int MQ = BN_ * TQ_;  // 2048
    const int MK = BN_ * TK_;  // 4096

    // Batched pre-attention weight transposes (Wq/Wk/Wv) in one launch;
    // grid y padded to max K/32 = 32, z selects the job.
    TsplitJob jq{Wq, WqT_h, WqT_l, DQ_, DQ_};
    TsplitJob jk{Wk, WkT_h, WkT_l, DC_, DQ_};
    TsplitJob jv{Wv, WvT_h, WvT_l, DC_, DQ_};
    tsplit3<<<dim3(DQ_ / 32, DQ_ / 32, 3), 256, 0, stream>>>(jq, jk, jv);

    // Q projection (scale DH^-0.5 folded into the hi/lo split); grid (8,32)
    gemm3<0, 2><<<dim3(DQ_ / 128, MQ / 64), 256, 0, stream>>>(
        x, nullptr, WqT_h, WqT_l, bq, 0.125f, Qhi, Qlo, MQ, DQ_, DQ_);

    // K + V projections batched in one launch; grid (8,64,2)
    GemmKVJob jobK{WkT_h, WkT_l, bk, Khi, Klo, 2};
    GemmKVJob jobV{WvT_h, WvT_l, bv, Vb, nullptr, 1};
    gemm_kv<<<dim3(DQ_ / 128, MK / 64, 2), 256, 0, stream>>>(
        ctx, jobK, jobV, MK, DQ_, DC_);

    // fused top-64 attention; writes attn hi/lo in place over Qhi/Qlo
    attn_topk<<<dim3(TQ_ / 16, NH_, BN_), 256, 0, stream>>>(
        Qhi, Qlo, Khi, Klo, Vb, msk, Qhi, Qlo);

    // output projection: split-A (attn hi/lo), fp32 out; grid (8,32)
    tsplit<<<dim3(DQ_ / 32, DQ_ / 32), 256, 0, stream>>>(Wo, WoT_h, WoT_l, DQ_, DQ_);
    gemm3<1, 0><<<dim3(DQ_ / 128, MQ / 64), 256, 0, stream>>>(
        Qhi, Qlo, WoT_h, WoT_l, bo, 1.0f, d_out, nullptr, MQ, DQ_, DQ_);
}

// Round 9
// 400.071 us; speedup vs baseline: 1.1173x; 1.0589x over previous
//
#include <hip/hip_runtime.h>
#include <hip/hip_bf16.h>
#include <cstdint>
#include <cstddef>

// Problem constants (from reference). Inputs/outputs are fp32 (verified round 4).
#define BN_ 2
#define TQ_ 1024
#define TK_ 2048
#define DQ_ 1024
#define DC_ 768
#define NH_ 16
#define DH_ 64
#define TOPK_ 64

typedef unsigned short u16;
typedef __attribute__((ext_vector_type(8))) short short8;   // 8 bf16 MFMA frag
typedef __attribute__((ext_vector_type(8))) u16   ushort8;  // 16B vector load
typedef __attribute__((ext_vector_type(4))) float floatx4;  // MFMA acc / float4

__device__ __forceinline__ float bf2f(u16 u) { return __uint_as_float(((unsigned)u) << 16); }
__device__ __forceinline__ u16 f2bf(float f) {  // round-to-nearest-even (manual)
    unsigned u = __float_as_uint(f);
    u += 0x7FFFu + ((u >> 16) & 1u);
    return (u16)(u >> 16);
}
// HW-converter variant for hot staging loops: compiler emits v_cvt_pk_bf16_f32
// pairs (m240: scalar cast beats hand asm). RNE == RNE -> bit-identical to
// f2bf for all non-NaN inputs (ours are definite).
__device__ __forceinline__ u16 f2bf_cvt(float f) {
    union { __hip_bfloat16 b; u16 u; } cv;
    cv.b = __float2bfloat16(f);
    return cv.u;
}
__device__ __forceinline__ float definite(float v, float repl) {
    return ((__float_as_uint(v) & 0x7F800000u) == 0x7F800000u) ? repl : v;
}
// monotone float<->uint mapping (ascending)
__device__ __forceinline__ unsigned mono(float f) {
    unsigned u = __float_as_uint(f);
    return (u & 0x80000000u) ? ~u : (u | 0x80000000u);
}
__device__ __forceinline__ float invmono(unsigned u) {
    return __uint_as_float((u & 0x80000000u) ? (u & 0x7FFFFFFFu) : ~u);
}
// async global(16B) -> LDS direct copy. LDS dest must be linear in lane
// (base + lane*16); the swizzle lives in the per-lane GLOBAL address
// (m173 pattern: linear LDS dest + pre-swizzled per-lane source).
__device__ __forceinline__ void gld16(const u16* g, u16* l) {
    __builtin_amdgcn_global_load_lds(
        (const __attribute__((address_space(1))) unsigned*)g,
        (__attribute__((address_space(3))) unsigned*)l, 16, 0, 0);
}
// 16-lane-group reductions (xor offsets 1,2,4,8 stay inside row-of-16 -> DPP)
__device__ __forceinline__ int gsum16(int x) {
#pragma unroll
    for (int o = 1; o < 16; o <<= 1) x += __shfl_xor(x, o);
    return x;
}
__device__ __forceinline__ int gmin16(int x) {
#pragma unroll
    for (int o = 1; o < 16; o <<= 1) { int y = __shfl_xor(x, o); x = (y < x) ? y : x; }
    return x;
}
__device__ __forceinline__ unsigned gmin16u(unsigned x) {
#pragma unroll
    for (int o = 1; o < 16; o <<= 1) { unsigned y = __shfl_xor((int)x, o); x = (y < x) ? y : x; }
    return x;
}
__device__ __forceinline__ unsigned gmax16u(unsigned x) {
#pragma unroll
    for (int o = 1; o < 16; o <<= 1) { unsigned y = __shfl_xor((int)x, o); x = (y > x) ? y : x; }
    return x;
}
__device__ __forceinline__ float gmax16f(float x) {
#pragma unroll
    for (int o = 1; o < 16; o <<= 1) x = fmaxf(x, __shfl_xor(x, o));
    return x;
}
__device__ __forceinline__ float gsum16f(float x) {
#pragma unroll
    for (int o = 1; o < 16; o <<= 1) x += __shfl_xor(x, o);
    return x;
}

// diagnostic: fill output with a recognizable constant (fp32 out)
__global__ void marker_kernel(float* __restrict__ out, int n, float val) {
    const int i = blockIdx.x * 256 + threadIdx.x;
    if (i < n) out[i] = val;
}

// ---------------------------------------------------------------------------
// Exact top-64 selection, qtr0 variant: 32 values/lane with IMPLICIT keys
// key(j) = (l16 + 16*j) << 11 (pre-scaled V byte offset, affine in register
// index j — no kk[32] array, which was the residual spill source at 64 VGPR).
// Early-exit when count==64 ({u >= X} exactly 64). Compact >X then tie-fill
// ==X ascending-key. Returns xval = invmono(X) (lower bound on kept min).
__device__ __forceinline__ float select_topk32_ik(const unsigned (&um)[32], int l16,
                                                  float* cvrow, int* ckrow) {
    unsigned X = 0u;
    bool done = false;
    for (int bit = 31; bit >= 0; --bit) {
        const unsigned C = X | (1u << bit);
        int c = 0;
#pragma unroll
        for (int j = 0; j < 32; ++j) c += (um[j] >= C) ? 1 : 0;
        c = gsum16(c);
        if (!done && c >= 64) X = C;
        if (c == 64) done = true;
        if (__all(done)) break;
    }
    // compact strictly-greater
    int myGt = 0;
#pragma unroll
    for (int j = 0; j < 32; ++j) myGt += (um[j] > X) ? 1 : 0;
    const int totalGt = gsum16(myGt);
    int pre = myGt;
#pragma unroll
    for (int off = 1; off < 16; off <<= 1) {
        const int tv = __shfl_up(pre, off);
        if (l16 >= off) pre += tv;
    }
    int wpos = pre - myGt;
#pragma unroll
    for (int j = 0; j < 32; ++j) {
        if (um[j] > X) {
            cvrow[wpos] = invmono(um[j]);
            ckrow[wpos] = (l16 + 16 * j) << 11;
            ++wpos;
        }
    }
    // tie-fill remaining slots with ==X entries, ascending key
    const float xval = invmono(X);
    int remaining = 64 - totalGt;
    int pos = totalGt;
    int lastkey = -1;
    while (remaining > 0) {
        int mykey = 0x7FFFFFFF;
#pragma unroll
        for (int j = 0; j < 32; ++j) {
            const int kj = (l16 + 16 * j) << 11;
            if (um[j] == X && kj > lastkey && kj < mykey) mykey = kj;
        }
        const int mn = gmin16(mykey);
        if (mn == 0x7FFFFFFF) break;
        if (mykey == mn) { cvrow[pos] = xval; ckrow[pos] = mn; }
        lastkey = mn;
        ++pos; --remaining;
    }
    return xval;
}

// ---------------------------------------------------------------------------
// Compact-phase select: NV values/lane (explicit scaled keys), z-space vs
// base. Same algorithm; writes separate value/key arrays.
template <int NV>
__device__ __forceinline__ float select_topk(const unsigned (&um)[NV], const int (&kk)[NV],
                                             unsigned base, int hb, int l16,
                                             float* cvrow, int* ckrow) {
    unsigned X = 0u;
    bool done = false;
    for (int bit = hb; bit >= 0; --bit) {
        const unsigned C = X | (1u << bit);
        int c = 0;
#pragma unroll
        for (int j = 0; j < NV; ++j) c += (um[j] >= C) ? 1 : 0;
        c = gsum16(c);
        if (!done && c >= 64) X = C;
        if (c == 64) done = true;
        if (__all(done)) break;
    }
    int myGt = 0;
#pragma unroll
    for (int j = 0; j < NV; ++j) myGt += (um[j] > X) ? 1 : 0;
    const int totalGt = gsum16(myGt);
    int pre = myGt;
#pragma unroll
    for (int off = 1; off < 16; off <<= 1) {
        const int tv = __shfl_up(pre, off);
        if (l16 >= off) pre += tv;
    }
    int wpos = pre - myGt;
#pragma unroll
    for (int j = 0; j < NV; ++j) {
        if (um[j] > X) {
            cvrow[wpos] = invmono(base + um[j]);
            ckrow[wpos] = kk[j];
            ++wpos;
        }
    }
    const float xval = invmono(base + X);
    int remaining = 64 - totalGt;
    int pos = totalGt;
    int lastkey = -1;
    while (remaining > 0) {
        int mykey = 0x7FFFFFFF;
#pragma unroll
        for (int j = 0; j < NV; ++j)
            if (um[j] == X && kk[j] > lastkey && kk[j] < mykey) mykey = kk[j];
        const int mn = gmin16(mykey);
        if (mn == 0x7FFFFFFF) break;
        if (mykey == mn) { cvrow[pos] = xval; ckrow[pos] = mn; }
        lastkey = mn;
        ++pos; --remaining;
    }
    return xval;
}

// ---------------------------------------------------------------------------
// Transpose + hi/lo-split: W fp32 [K][N] -> Wh,Wl bf16 [N][K]
// Batched variant: blockIdx.z selects among up to 3 independent weights
// (saves 2 kernel launches + stream bubbles vs separate dispatches).
struct TsplitJob { const float* W; u16* Wh; u16* Wl; int K; int N; };

__global__ void __launch_bounds__(256) tsplit3(TsplitJob j0, TsplitJob j1, TsplitJob j2) {
    const TsplitJob j = (blockIdx.z == 0) ? j0 : (blockIdx.z == 1) ? j1 : j2;
    const int bk = blockIdx.y * 32;
    if (bk >= j.K) return;                      // grids padded to max K/32
    __shared__ float t[32][33];
    const int x = threadIdx.x & 31, y = threadIdx.x >> 5;   // y in 0..7
    const int bn = blockIdx.x * 32;
#pragma unroll
    for (int i = 0; i < 32; i += 8) t[y + i][x] = j.W[(size_t)(bk + y + i) * j.N + bn + x];
    __syncthreads();
#pragma unroll
    for (int i = 0; i < 32; i += 8) {
        const float f = t[x][y + i];            // = W[bk+x][bn+y+i]
        const u16 hi = f2bf(f);
        const size_t o = (size_t)(bn + y + i) * j.K + bk + x;
        j.Wh[o] = hi;
        j.Wl[o] = f2bf(f - bf2f(hi));
    }
}

__global__ void __launch_bounds__(256) tsplit(const float* __restrict__ W,
                                              u16* __restrict__ Wh, u16* __restrict__ Wl,
                                              int K, int N) {
    __shared__ float t[32][33];
    const int x = threadIdx.x & 31, y = threadIdx.x >> 5;
    const int bn = blockIdx.x * 32, bk = blockIdx.y * 32;
#pragma unroll
    for (int i = 0; i < 32; i += 8) t[y + i][x] = W[(size_t)(bk + y + i) * N + bn + x];
    __syncthreads();
#pragma unroll
    for (int i = 0; i < 32; i += 8) {
        const float f = t[x][y + i];
        const u16 hi = f2bf(f);
        const size_t o = (size_t)(bn + y + i) * K + bk + x;
        Wh[o] = hi;
        Wl[o] = f2bf(f - bf2f(hi));
    }
}

// ---------------------------------------------------------------------------
// GEMM (round-11 proven structure; r19: global_load_lds staging for pre-split
// operands; r21: A-split conversion via HW cvt (v_cvt_pk_bf16_f32) — RNE
// bit-identical to manual f2bf, fewer VALU ops in the hot staging loop).
// C[M][N] = A[M][K] * W[K][N] + bias, * scale.
// B pre-transposed & split: Bh/Bl bf16 [N][K]. Tile 64(M) x 128(N), BK=64.
// XOR-swizzled UNPADDED LDS: row m chunk c stored at slot m*8 + (c ^ (m&7)).
// 4 waves 2x2: wave tile 32(m) x 64(n) = 2x4 mfma_16x16x32, 3-term split
// (ah*bh + al*bh + ah*bl). LDS 48KB -> 3 WG/CU.
// ASPLIT 0: A fp32 (split at stage). ASPLIT 1: A bf16 hi/lo (global_load_lds).
// OMODE 0: fp32 out. 1: bf16 out. 2: hi/lo pair out.
template <int ASPLIT, int OMODE>
__global__ void __launch_bounds__(256) gemm3(
    const void* __restrict__ Ap, const void* __restrict__ Alp,
    const u16* __restrict__ Bh, const u16* __restrict__ Bl,
    const float* __restrict__ bias, float scale,
    void* __restrict__ out0, void* __restrict__ out1,
    int M, int N, int K) {
    __shared__ u16 Ahs[64 * 64];    // 8 KB   [m][k] hi, swizzled
    __shared__ u16 Als[64 * 64];    // 8 KB   lo
    __shared__ u16 Bhs[128 * 64];   // 16 KB  [n][k] hi, swizzled
    __shared__ u16 Bls[128 * 64];   // 16 KB  lo

    const int tid = threadIdx.x;
    const int lane = tid & 63, wave = tid >> 6;
    const int wm = wave >> 1, wn = wave & 1;
    const int quad = lane >> 4, l16 = lane & 15;
    const int bm = blockIdx.y * 64, bn = blockIdx.x * 128;

    floatx4 acc[2][4] = {};

    for (int k0 = 0; k0 < K; k0 += 64) {
        __syncthreads();
        // ---- stage A: 64 rows x 64 cols = 512 slots of 8 elems, 2 per thread
#pragma unroll
        for (int s2 = 0; s2 < 2; ++s2) {
            const int slot = tid + s2 * 256;
            const int m = slot >> 3, cpos = slot & 7;
            const int c = cpos ^ (m & 7);
            const size_t aoff = (size_t)(bm + m) * K + k0 + c * 8;
            if constexpr (ASPLIT == 0) {
                const float* f = (const float*)Ap + aoff;
                const floatx4 a = *(const floatx4*)f;
                const floatx4 b = *(const floatx4*)(f + 4);
                ushort8 hi, lo;
#pragma unroll
                for (int j = 0; j < 4; ++j) {
                    const u16 t = f2bf_cvt(a[j]);
                    hi[j] = t; lo[j] = f2bf_cvt(a[j] - bf2f(t));
                    const u16 t2 = f2bf_cvt(b[j]);
                    hi[4 + j] = t2; lo[4 + j] = f2bf_cvt(b[j] - bf2f(t2));
                }
                *(ushort8*)&Ahs[slot * 8] = hi;
                *(ushort8*)&Als[slot * 8] = lo;
            } else {
                gld16((const u16*)Ap  + aoff, &Ahs[slot * 8]);
                gld16((const u16*)Alp + aoff, &Als[slot * 8]);
            }
        }
        // ---- stage B: 128 rows x 64 cols = 1024 slots, 4 per thread,
        //      async direct-to-LDS (dest linear in lane; swizzle in gaddr)
#pragma unroll
        for (int s4 = 0; s4 < 4; ++s4) {
            const int slot = tid + s4 * 256;
            const int n = slot >> 3, cpos = slot & 7;
            const int c = cpos ^ (n & 7);
            const size_t boff = (size_t)(bn + n) * K + k0 + c * 8;
            gld16(Bh + boff, &Bhs[slot * 8]);
            gld16(Bl + boff, &Bls[slot * 8]);
        }
        __syncthreads();
#pragma unroll
        for (int s = 0; s < 2; ++s) {
            short8 ah[2], al[2], bh[4], bl[4];
#pragma unroll
            for (int mt = 0; mt < 2; ++mt) {
                const int m = wm * 32 + mt * 16 + l16;
                const int cs = s * 4 + quad;
                const int slot = m * 8 + (cs ^ (m & 7));
                ah[mt] = *(const short8*)&Ahs[slot * 8];
                al[mt] = *(const short8*)&Als[slot * 8];
            }
#pragma unroll
            for (int nt = 0; nt < 4; ++nt) {
                const int n = wn * 64 + nt * 16 + l16;
                const int cs = s * 4 + quad;
                const int slot = n * 8 + (cs ^ (n & 7));
                bh[nt] = *(const short8*)&Bhs[slot * 8];
                bl[nt] = *(const short8*)&Bls[slot * 8];
            }
#pragma unroll
            for (int mt = 0; mt < 2; ++mt)
#pragma unroll
                for (int nt = 0; nt < 4; ++nt) {
                    acc[mt][nt] = __builtin_amdgcn_mfma_f32_16x16x32_bf16(ah[mt], bh[nt], acc[mt][nt], 0, 0, 0);
                    acc[mt][nt] = __builtin_amdgcn_mfma_f32_16x16x32_bf16(al[mt], bh[nt], acc[mt][nt], 0, 0, 0);
                    acc[mt][nt] = __builtin_amdgcn_mfma_f32_16x16x32_bf16(ah[mt], bl[nt], acc[mt][nt], 0, 0, 0);
                }
        }
    }

#pragma unroll
    for (int mt = 0; mt < 2; ++mt) {
#pragma unroll
        for (int nt = 0; nt < 4; ++nt) {
            const int col = bn + wn * 64 + nt * 16 + l16;
            const float bcol = bias[col];
#pragma unroll
            for (int r = 0; r < 4; ++r) {
                const int row = bm + wm * 32 + mt * 16 + quad * 4 + r;
                const float val = definite((acc[mt][nt][r] + bcol) * scale, 0.0f);
                const size_t idx = (size_t)row * N + col;
                if constexpr (OMODE == 0) {
                    ((float*)out0)[idx] = val;
                } else if constexpr (OMODE == 1) {
                    ((u16*)out0)[idx] = f2bf(val);
                } else {
                    const u16 hi = f2bf(val);
                    ((u16*)out0)[idx] = hi;
                    ((u16*)out1)[idx] = f2bf(val - bf2f(hi));
                }
            }
        }
    }
}

// ---------------------------------------------------------------------------
// Batched K+V projection: one launch, blockIdx.z selects the job. Both jobs
// share A = ctx (fp32, split at stage with HW cvt), M, N, K; differ in
// B/bias/out/omode. NOTE: WkT/WvT live in d_out (dead until final GEMM).
struct GemmKVJob { const u16* Bh; const u16* Bl; const float* bias;
                   void* out0; void* out1; int omode; };

__global__ void __launch_bounds__(256) gemm_kv(
    const float* __restrict__ Ap, GemmKVJob j0, GemmKVJob j1,
    int M, int N, int K) {
    const GemmKVJob j = (blockIdx.z == 0) ? j0 : j1;
    __shared__ u16 Ahs[64 * 64];
    __shared__ u16 Als[64 * 64];
    __shared__ u16 Bhs[128 * 64];
    __shared__ u16 Bls[128 * 64];

    const int tid = threadIdx.x;
    const int lane = tid & 63, wave = tid >> 6;
    const int wm = wave >> 1, wn = wave & 1;
    const int quad = lane >> 4, l16 = lane & 15;
    const int bm = blockIdx.y * 64, bn = blockIdx.x * 128;

    floatx4 acc[2][4] = {};

    for (int k0 = 0; k0 < K; k0 += 64) {
        __syncthreads();
#pragma unroll
        for (int s2 = 0; s2 < 2; ++s2) {
            const int slot = tid + s2 * 256;
            const int m = slot >> 3, cpos = slot & 7;
            const int c = cpos ^ (m & 7);
            const size_t aoff = (size_t)(bm + m) * K + k0 + c * 8;
            const float* f = Ap + aoff;
            const floatx4 a = *(const floatx4*)f;
            const floatx4 b = *(const floatx4*)(f + 4);
            ushort8 hi, lo;
#pragma unroll
            for (int jj = 0; jj < 4; ++jj) {
                const u16 t = f2bf_cvt(a[jj]);
                hi[jj] = t; lo[jj] = f2bf_cvt(a[jj] - bf2f(t));
                const u16 t2 = f2bf_cvt(b[jj]);
                hi[4 + jj] = t2; lo[4 + jj] = f2bf_cvt(b[jj] - bf2f(t2));
            }
            *(ushort8*)&Ahs[slot * 8] = hi;
            *(ushort8*)&Als[slot * 8] = lo;
        }
#pragma unroll
        for (int s4 = 0; s4 < 4; ++s4) {
            const int slot = tid + s4 * 256;
            const int n = slot >> 3, cpos = slot & 7;
            const int c = cpos ^ (n & 7);
            const size_t boff = (size_t)(bn + n) * K + k0 + c * 8;
            gld16(j.Bh + boff, &Bhs[slot * 8]);
            gld16(j.Bl + boff, &Bls[slot * 8]);
        }
        __syncthreads();
#pragma unroll
        for (int s = 0; s < 2; ++s) {
            short8 ah[2], al[2], bh[4], bl[4];
#pragma unroll
            for (int mt = 0; mt < 2; ++mt) {
                const int m = wm * 32 + mt * 16 + l16;
                const int cs = s * 4 + quad;
                const int slot = m * 8 + (cs ^ (m & 7));
                ah[mt] = *(const short8*)&Ahs[slot * 8];
                al[mt] = *(const short8*)&Als[slot * 8];
            }
#pragma unroll
            for (int nt = 0; nt < 4; ++nt) {
                const int n = wn * 64 + nt * 16 + l16;
                const int cs = s * 4 + quad;
                const int slot = n * 8 + (cs ^ (n & 7));
                bh[nt] = *(const short8*)&Bhs[slot * 8];
                bl[nt] = *(const short8*)&Bls[slot * 8];
            }
#pragma unroll
            for (int mt = 0; mt < 2; ++mt)
#pragma unroll
                for (int nt = 0; nt < 4; ++nt) {
                    acc[mt][nt] = __builtin_amdgcn_mfma_f32_16x16x32_bf16(ah[mt], bh[nt], acc[mt][nt], 0, 0, 0);
                    acc[mt][nt] = __builtin_amdgcn_mfma_f32_16x16x32_bf16(al[mt], bh[nt], acc[mt][nt], 0, 0, 0);
                    acc[mt][nt] = __builtin_amdgcn_mfma_f32_16x16x32_bf16(ah[mt], bl[nt], acc[mt][nt], 0, 0, 0);
                }
        }
    }

#pragma unroll
    for (int mt = 0; mt < 2; ++mt) {
#pragma unroll
        for (int nt = 0; nt < 4; ++nt) {
            const int col = bn + wn * 64 + nt * 16 + l16;
            const float bcol = j.bias[col];
#pragma unroll
            for (int r = 0; r < 4; ++r) {
                const int row = bm + wm * 32 + mt * 16 + quad * 4 + r;
                const float val = definite(acc[mt][nt][r] + bcol, 0.0f);
                const size_t idx = (size_t)row * N + col;
                if (j.omode == 1) {
                    ((u16*)j.out0)[idx] = f2bf(val);
                } else {
                    const u16 hi = f2bf(val);
                    ((u16*)j.out0)[idx] = hi;
                    ((u16*)j.out1)[idx] = f2bf(val - bf2f(hi));
                }
            }
        }
    }
}

// ---------------------------------------------------------------------------
// Fused attention — EXACT round-20 code (best measured: 215.6 us, WRITE 8MB,
// FETCH 100MB, zero spill, 4 WG/CU).
// Cross-round ledger (attn us / WRITE MB / FETCH MB / conflicts):
//   r18 safe cuts, 40960 LDS:   218 / 16  / 105 / 6.6M
//   r20 32768 LDS, zero spill:  215.6/ 8  / 100 / 6.6M  <- BEST, restored
//   r21 +lgswz +XCD swizzle:    258 / 187 / 67  / 5.6M  (both reverted)
//   r22 +lgswz only:            236 / 84  / 139 / 5.6M  (lgswz reverted)
// CLOSED paths (counter-backed, do not revisit):
//   * 5 WG/CU: does not materialize at 32768B LDS + VGPR 64 + zero spill
//     (r20: occ stays 43%) -> 4 WG/CU is the hw ceiling for this shape.
//   * XCD block swizzle: in-place 128B-row-segment outputs rely on the
//     default mapping's write locality (all 16 h-writers of a q-row on one
//     XCD). Swizzle -> partial-row evictions, WRITE x23 (r21).
//   * lgswz LDS swizzle: XOR breaks affine ds-address immediates -> register
//     pressure at pinned VGPR 64 -> scratch spills (+115MB HBM, r22). LDS
//     swizzles must keep addresses affine in the unroll index.
// Remaining theory: ~80% stall from dependent shfl/LDS chains (bit-search
// selects) at 4 WG/CU; next candidate = 2-bit radix select (halves chain).
__global__ void __launch_bounds__(256, 4) attn_topk(
    const u16* Qhi, const u16* Qlo,     // aliased with outputs - no __restrict__
    const u16* __restrict__ Khi, const u16* __restrict__ Klo,
    const u16* __restrict__ Vb16, const void* __restrict__ maskp,
    u16* attnH, u16* attnL) {
    __shared__ float lg[16][512];     // 32768 B total (carry aliased inside)

#define CV_(row) (&lg[row][256])
#define CK_(row) (((int*)&lg[row][0]) + 320)

    const int tid = threadIdx.x;
    const int lane = tid & 63, wave = tid >> 6;
    const int quad = lane >> 4, l16 = lane & 15;
    const int rowg = wave * 4 + quad;              // this lane's selection row
    const int b = blockIdx.z, h = blockIdx.y, q0 = blockIdx.x * 16;

    // ---- mask dtype probe: per-wave, barrier-free (first 1024 u16 = 2 KB)
    int mmode;
    {
        bool cbyte = false, cbf = false, cf32 = false;
#pragma unroll
        for (int j = 0; j < 16; ++j) {
            const int i = lane + 64 * j;
            const unsigned v = ((const u16*)maskp)[i];
            cbyte |= (v == 0x0100u || v == 0x0101u) || ((i & 1) && v == 0x0001u);
            cbf   |= (!(i & 1)) && v == 0x3F80u;
            cf32  |= (i & 1) && v == 0x3F80u;
        }
        const bool abf = __any(cbf), af32 = __any(cf32), abyte = __any(cbyte);
        mmode = abf ? 2 : (af32 ? 3 : (abyte ? 1 : 0));
    }

    // ---- Q fragments (A-operand: m=lane&15, k=quad*8+j), two k-steps of 32
    short8 qh[2], ql[2];
    {
        const size_t base = (size_t)(b * TQ_ + q0 + l16) * DQ_ + h * DH_ + quad * 8;
        qh[0] = *(const short8*)(Qhi + base);
        qh[1] = *(const short8*)(Qhi + base + 32);
        ql[0] = *(const short8*)(Qlo + base);
        ql[1] = *(const short8*)(Qlo + base + 32);
    }

    for (int qtr = 0; qtr < 4; ++qtr) {
        if (qtr == 0) {
            // ---- full logit phase: write all 512 per row
#pragma unroll 2
            for (int t = 0; t < 8; ++t) {
                const int key = wave * 128 + t * 16 + l16;
                const size_t kb = (size_t)(b * TK_ + key) * DQ_ + h * DH_ + quad * 8;
                const short8 kh0 = *(const short8*)(Khi + kb);
                const short8 kh1 = *(const short8*)(Khi + kb + 32);
                const short8 kl0 = *(const short8*)(Klo + kb);
                const short8 kl1 = *(const short8*)(Klo + kb + 32);
                floatx4 acc = {};
                acc = __builtin_amdgcn_mfma_f32_16x16x32_bf16(qh[0], kh0, acc, 0, 0, 0);
                acc = __builtin_amdgcn_mfma_f32_16x16x32_bf16(ql[0], kh0, acc, 0, 0, 0);
                acc = __builtin_amdgcn_mfma_f32_16x16x32_bf16(qh[0], kl0, acc, 0, 0, 0);
                acc = __builtin_amdgcn_mfma_f32_16x16x32_bf16(qh[1], kh1, acc, 0, 0, 0);
                acc = __builtin_amdgcn_mfma_f32_16x16x32_bf16(ql[1], kh1, acc, 0, 0, 0);
                acc = __builtin_amdgcn_mfma_f32_16x16x32_bf16(qh[1], kl1, acc, 0, 0, 0);
                const int midx = b * TK_ + key;
                bool masked;
                if (mmode == 2)      masked = ((const u16*)maskp)[midx] != 0;
                else if (mmode == 3) masked = ((const float*)maskp)[midx] != 0.0f;
                else if (mmode == 1) masked = ((const unsigned char*)maskp)[midx] != 0;
                else                 masked = ((const int*)maskp)[midx] != 0;
#pragma unroll
                for (int r = 0; r < 4; ++r)
                    lg[quad * 4 + r][key] = masked ? -3.0e38f : acc[r];
            }
            __syncthreads();

            // ---- full select over 32 new values, implicit keys (carry is
            // -inf in qtr0 and provably never selected: every logit >= -3e38)
            unsigned um[32];
#pragma unroll
            for (int j = 0; j < 32; ++j) um[j] = mono(lg[rowg][l16 + 16 * j]);
            const float th = select_topk32_ik(um, l16, CV_(rowg), CK_(rowg));
            if (l16 == 0) {
                lg[rowg][255] = th;                 // filter threshold for next qtr
                ((int*)&lg[rowg][0])[511] = 0;      // reset candidate counter
            }
        } else {
            // ---- filtered logit phase: push only survivors (> th) compactly
            float cmrow[4];
#pragma unroll
            for (int r = 0; r < 4; ++r) cmrow[r] = lg[quad * 4 + r][255];
#pragma unroll 2
            for (int t = 0; t < 8; ++t) {
                const int key = qtr * 512 + wave * 128 + t * 16 + l16;
                const size_t kb = (size_t)(b * TK_ + key) * DQ_ + h * DH_ + quad * 8;
                const short8 kh0 = *(const short8*)(Khi + kb);
                const short8 kh1 = *(const short8*)(Khi + kb + 32);
                const short8 kl0 = *(const short8*)(Klo + kb);
                const short8 kl1 = *(const short8*)(Klo + kb + 32);
                floatx4 acc = {};
                acc = __builtin_amdgcn_mfma_f32_16x16x32_bf16(qh[0], kh0, acc, 0, 0, 0);
                acc = __builtin_amdgcn_mfma_f32_16x16x32_bf16(ql[0], kh0, acc, 0, 0, 0);
                acc = __builtin_amdgcn_mfma_f32_16x16x32_bf16(qh[0], kl0, acc, 0, 0, 0);
                acc = __builtin_amdgcn_mfma_f32_16x16x32_bf16(qh[1], kh1, acc, 0, 0, 0);
                acc = __builtin_amdgcn_mfma_f32_16x16x32_bf16(ql[1], kh1, acc, 0, 0, 0);
                acc = __builtin_amdgcn_mfma_f32_16x16x32_bf16(qh[1], kl1, acc, 0, 0, 0);
                const int midx = b * TK_ + key;
                bool masked;
                if (mmode == 2)      masked = ((const u16*)maskp)[midx] != 0;
                else if (mmode == 3) masked = ((const float*)maskp)[midx] != 0.0f;
                else if (mmode == 1) masked = ((const unsigned char*)maskp)[midx] != 0;
                else                 masked = ((const int*)maskp)[midx] != 0;
#pragma unroll
                for (int r = 0; r < 4; ++r) {
                    const float val = masked ? -3.0e38f : acc[r];
                    if (val > cmrow[r]) {
                        const int row = quad * 4 + r;
                        const int pos = atomicAdd((int*)&lg[row][511], 1);
                        if (pos < 127) {
                            lg[row][pos] = val;
                            ((int*)&lg[row][0])[128 + pos] = key << 11;
                        }
                    }
                }
            }
            __syncthreads();

            // ---- compact select: 8 candidates + 4 carry per lane, z-space
            unsigned uc[4]; int ck4[4];
#pragma unroll
            for (int t = 0; t < 4; ++t) {
                uc[t] = mono(CV_(rowg)[l16 + 16 * t]);
                ck4[t] = CK_(rowg)[l16 + 16 * t];
            }
            unsigned cm = uc[0];
            cm = (uc[1] < cm) ? uc[1] : cm;
            cm = (uc[2] < cm) ? uc[2] : cm;
            cm = (uc[3] < cm) ? uc[3] : cm;
            cm = gmin16u(cm);
            int cnt = ((int*)&lg[rowg][0])[511];
            if (cnt > 127) cnt = 127;

            unsigned zm[12]; int kk[12];
            unsigned zmx = 0;
#pragma unroll
            for (int i = 0; i < 8; ++i) {
                const int idx = l16 + 16 * i;          // 0..127
                const bool valid = idx < cnt;
                const float v = lg[rowg][idx];
                const int k = ((int*)&lg[rowg][0])[128 + idx];
                const unsigned mv = mono(v);
                // CLAMP: th (early-exit X) can sit below the true carry-min cm;
                // mv <= cm candidates can never be in the exact top-64 -> pads.
                const bool live = valid && (mv > cm);
                zm[i] = live ? (mv - cm) : 0u;
                kk[i] = live ? k : 0x7FFFFFFF;
                zmx = (zm[i] > zmx) ? zm[i] : zmx;
            }
#pragma unroll
            for (int t = 0; t < 4; ++t) {
                zm[8 + t] = uc[t] - cm;
                kk[8 + t] = ck4[t];
                zmx = (zm[8 + t] > zmx) ? zm[8 + t] : zmx;
            }
            zmx = gmax16u(zmx);
            const int hb = 31 - __clz(zmx | 1u);
            const float th = select_topk<12>(zm, kk, cm, hb, l16, CV_(rowg), CK_(rowg));
            if (l16 == 0) {
                lg[rowg][255] = th;
                ((int*)&lg[rowg][0])[511] = 0;
            }
        }
        if (qtr < 3) __syncthreads();   // th/counter + lg reuse next quarter
    }

    // ---- softmax over 64 kept entries (group-parallel; same-wave LDS ordering)
    {
        float v4[4];
#pragma unroll
        for (int t = 0; t < 4; ++t) v4[t] = CV_(rowg)[l16 + 16 * t];
        float m = fmaxf(fmaxf(v4[0], v4[1]), fmaxf(v4[2], v4[3]));
        m = gmax16f(m);
        float p4[4], S = 0.f;
#pragma unroll
        for (int t = 0; t < 4; ++t) { p4[t] = __expf(v4[t] - m); S += p4[t]; }
        S = gsum16f(S);
        const float inv = 1.0f / S;
#pragma unroll
        for (int t = 0; t < 4; ++t) CV_(rowg)[l16 + 16 * t] = p4[t] * inv;
    }

    // ---- weighted bf16-V gather: row-pairs, dword loads (2 dims/lane).
    // Carry keys are pre-scaled V byte offsets -> no per-entry 64-bit
    // multiply; bf16 unpack is 1 shl + 1 and.
    const int half = lane >> 5, l32 = lane & 31;
    const char* Vrow = (const char*)(Vb16 + (size_t)b * TK_ * DQ_ + h * DH_ + l32 * 2);
#pragma unroll
    for (int rp = 0; rp < 2; ++rp) {
        const int row = wave * 4 + rp * 2 + half;
        float a0 = 0.f, a1 = 0.f;
#pragma unroll 4
        for (int e = 0; e < 64; ++e) {
            const float w = CV_(row)[e];
            const int koff = CK_(row)[e];
            const unsigned v2 = *(const unsigned*)(Vrow + koff);
            a0 = fmaf(w, __uint_as_float(v2 << 16), a0);
            a1 = fmaf(w, __uint_as_float(v2 & 0xFFFF0000u), a1);
        }
        a0 = definite(a0, 0.0f);
        a1 = definite(a1, 0.0f);
        const size_t o = (size_t)(b * TQ_ + q0 + row) * DQ_ + h * DH_ + l32 * 2;
        const u16 h0 = f2bf(a0), h1 = f2bf(a1);
        const u16 l0 = f2bf(a0 - bf2f(h0)), l1 = f2bf(a1 - bf2f(h1));
        *(unsigned*)(attnH + o) = (unsigned)h0 | ((unsigned)h1 << 16);
        *(unsigned*)(attnL + o) = (unsigned)l0 | ((unsigned)l1 << 16);
    }
#undef CV_
#undef CK_
}

// ---------------------------------------------------------------------------
extern "C" void kernel_launch(void* const* d_in, const int* in_sizes, int n_in,
                              void* d_out, int out_size, void* d_ws, size_t ws_size,
                              hipStream_t stream) {
    static const int exp_sizes[11] = {2097152, 3145728, 4096, 1048576, 1024,
                                      786432, 1024, 786432, 1024, 1048576, 1024};
    if (n_in != 11) {
        marker_kernel<<<(out_size + 255) / 256, 256, 0, stream>>>((float*)d_out, out_size,
                                                                  (float)(150 + n_in));
        return;
    }
    for (int i = 0; i < 11; ++i)
        if (in_sizes[i] != exp_sizes[i]) {
            marker_kernel<<<(out_size + 255) / 256, 256, 0, stream>>>((float*)d_out, out_size,
                                                                      (float)(200 + i));
            return;
        }

    const float* x   = (const float*)d_in[0];
    const float* ctx = (const float*)d_in[1];
    const void*  msk = d_in[2];
    const float* Wq = (const float*)d_in[3];
    const float* bq = (const float*)d_in[4];
    const float* Wk = (const float*)d_in[5];
    const float* bk = (const float*)d_in[6];
    const float* Wv = (const float*)d_in[7];
    const float* bv = (const float*)d_in[8];
    const float* Wo = (const float*)d_in[9];
    const float* bo = (const float*)d_in[10];

    // ---- workspace: exactly 32 MB (verified sufficient)
    const size_t SZ_Q = (size_t)BN_ * TQ_ * DQ_ * 2;   // 4 MB
    const size_t SZ_K = (size_t)BN_ * TK_ * DQ_ * 2;   // 8 MB
    const size_t NEED = 2 * SZ_Q + 2 * SZ_K + SZ_K;    // 32 MB
    if (ws_size < NEED) {
        marker_kernel<<<(out_size + 255) / 256, 256, 0, stream>>>(
            (float*)d_out, out_size, (float)(ws_size >> 20));
        return;
    }

    char* ws = (char*)d_ws;
    u16* Qhi = (u16*)(ws);
    u16* Qlo = (u16*)(ws + SZ_Q);
    u16* Khi = (u16*)(ws + 2 * SZ_Q);
    u16* Klo = (u16*)(ws + 2 * SZ_Q + SZ_K);
    u16* Vb  = (u16*)(ws + 2 * SZ_Q + 2 * SZ_K);

    // weight-split scratch carved from regions dead at that moment.
    // K+V projections run in ONE launch, so WkT and WvT must both live
    // outside {Khi, Klo, Vb} — d_out (8 MB, dead until final GEMM) holds
    // WvT [0,3MB) + WkT [3,6MB). WqT stays in Khi (Q-proj, a separate earlier
    // launch, completes before gemm_kv writes Khi).
    u16* WqT_h = Khi;                      // Khi unwritten until K-proj
    u16* WqT_l = Khi + (size_t)DQ_ * DQ_;
    u16* WvT_h = (u16*)d_out;              // d_out dead until final GEMM
    u16* WvT_l = WvT_h + (size_t)DC_ * DQ_;
    u16* WkT_h = WvT_h + 2 * (size_t)DC_ * DQ_;
    u16* WkT_l = WvT_h + 3 * (size_t)DC_ * DQ_;
    u16* WoT_h = Khi;                      // Khi dead after attention
    u16* WoT_l = Khi + (size_t)DQ_ * DQ_;

    const int MQ = BN_ * TQ_;  // 2048
    const int MK = BN_ * TK_;  // 4096

    // Batched pre-attention weight transposes (Wq/Wk/Wv) in one launch;
    // grid y padded to max K/32 = 32, z selects the job.
    TsplitJob jq{Wq, WqT_h, WqT_l, DQ_, DQ_};
    TsplitJob jk{Wk, WkT_h, WkT_l, DC_, DQ_};
    TsplitJob jv{Wv, WvT_h, WvT_l, DC_, DQ_};
    tsplit3<<<dim3(DQ_ / 32, DQ_ / 32, 3), 256, 0, stream>>>(jq, jk, jv);

    // Q projection (scale DH^-0.5 folded into the hi/lo split); grid (8,32)
    gemm3<0, 2><<<dim3(DQ_ / 128, MQ / 64), 256, 0, stream>>>(
        x, nullptr, WqT_h, WqT_l, bq, 0.125f, Qhi, Qlo, MQ, DQ_, DQ_);

    // K + V projections batched in one launch; grid (8,64,2)
    GemmKVJob jobK{WkT_h, WkT_l, bk, Khi, Klo, 2};
    GemmKVJob jobV{WvT_h, WvT_l, bv, Vb, nullptr, 1};
    gemm_kv<<<dim3(DQ_ / 128, MK / 64, 2), 256, 0, stream>>>(
        ctx, jobK, jobV, MK, DQ_, DC_);

    // fused top-64 attention; writes attn hi/lo in place over Qhi/Qlo
    attn_topk<<<dim3(TQ_ / 16, NH_, BN_), 256, 0, stream>>>(
        Qhi, Qlo, Khi, Klo, Vb, msk, Qhi, Qlo);

    // output projection: split-A (attn hi/lo), fp32 out; grid (8,32)
    tsplit<<<dim3(DQ_ / 32, DQ_ / 32), 256, 0, stream>>>(Wo, WoT_h, WoT_l, DQ_, DQ_);
    gemm3<1, 0><<<dim3(DQ_ / 128, MQ / 64), 256, 0, stream>>>(
        Qhi, Qlo, WoT_h, WoT_l, bo, 1.0f, d_out, nullptr, MQ, DQ_, DQ_);
}